// Round 10
// baseline (520.381 us; speedup 1.0000x reference)
//
#include <hip/hip_runtime.h>

// ---------------------------------------------------------------------------
// PointTransformerBlock, MI355X.  R22 = R21 (best passing, 497us) + tail
// visibility + tail trims; k_edge BODY UNTOUCHED:
//  - k_edge split into TWO half-range dispatches (~87us each) so the rocprof
//    top-5 finally reveals the ~323us unprofiled tail (stable across 6
//    rounds; bottom-up estimates only explain ~130us).  Runs crossing the
//    split boundary already use atomics -> correctness preserved.
//  - Zero-fill kernel removed: incl scan-scratch re-aliased into spair's
//    buffer (dead before scatter writes it) instead of accg, so sg+accg
//    (contiguous 51.2MB) are zeroed by ONE hipMemsetAsync at stream start.
//  - R21 k_edge per-tile structure kept: v-permute contiguous 32B gather,
//    transposed GEMMs, an_W2 in regs, pay-fused SD, reg tile state, zero
//    per-tile barriers, launch_bounds(256,4), LDS 38.9KB.
//  MFMA layouts (HW-verified, guide §3): A[m=lane&15][k=q*8+j],
//  B[k=q*8+j][n=lane&15], C/D col=lane&15 row=q*4+r.
// ---------------------------------------------------------------------------

typedef __bf16 bf16x8 __attribute__((ext_vector_type(8)));
typedef float f32x4 __attribute__((ext_vector_type(4)));

__device__ inline unsigned short f2bf(float f) {
  return __builtin_bit_cast(unsigned short, (__bf16)f);   // v_cvt (RNE)
}
__device__ inline float bf2f(unsigned short s) {
  return __uint_as_float(((unsigned int)s) << 16);
}
__device__ inline bf16x8 ld_bf8(const unsigned short* p) {
  union { uint4 i; bf16x8 v; } u;
  u.i = *(const uint4*)p;
  return u.v;
}
// packed f32->2xbf16 (gfx950; no builtin -- guide T12/m240). dst.lo=cvt(lo).
__device__ inline unsigned int cvt_pk_bf16(float lo, float hi) {
  unsigned int r;
  asm("v_cvt_pk_bf16_f32 %0, %1, %2" : "=v"(r) : "v"(lo), "v"(hi));
  return r;
}

// --------------------- prep kernel with fused histogram --------------------

__global__ __launch_bounds__(256) void k_prep_hist(
    const float* __restrict__ W_in, const float* __restrict__ W_dst,
    const float* __restrict__ W_src, const float* __restrict__ W_lin,
    const float* __restrict__ pn_W2, const float* __restrict__ an_W1,
    const float* __restrict__ an_W2, const float* __restrict__ W_out,
    unsigned short* __restrict__ wt,
    const int* __restrict__ dst, int* __restrict__ hist, int E) {
  int t = threadIdx.x;
  if (blockIdx.x >= 8) {
    int e = (blockIdx.x - 8) * 256 + t;
    if (e < E) atomicAdd(&hist[dst[e]], 1);
    return;
  }
  const float* Ws[8] = {W_in, W_dst, W_src, W_lin, pn_W2, an_W1, an_W2, W_out};
  const float* W = Ws[blockIdx.x];
  unsigned short* o = wt + (size_t)blockIdx.x * 4608;
#pragma unroll
  for (int i = 0; i < 16; ++i) {
    int e = i * 256 + t;           // e = k*64 + n  (coalesced read)
    int k = e >> 6, n = e & 63;
    o[n * 72 + k] = f2bf(W[e]);    // wt[n][k] = W^T[n][k]
  }
}

// ------------------------------ sort kernels -------------------------------

// scan3 with inline block-offset: reduce bsum[0..blockIdx) in-block.
// Requires gridDim <= 256 (N <= 262144).
__global__ __launch_bounds__(256) void k_scan3(
    const int* __restrict__ incl, const int* __restrict__ hist,
    const int* __restrict__ bsum, int* __restrict__ cursor, int N) {
  __shared__ int red[256];
  int t = threadIdx.x;
  red[t] = (t < (int)blockIdx.x) ? bsum[t] : 0;
  __syncthreads();
#pragma unroll
  for (int off = 128; off; off >>= 1) {
    if (t < off) red[t] += red[t + off];
    __syncthreads();
  }
  int bo = red[0];
  int base = blockIdx.x * 1024 + t * 4;
#pragma unroll
  for (int i = 0; i < 4; ++i) {
    int id = base + i;
    if (id < N) cursor[id] = bo + incl[id] - hist[id];
  }
}

// scatter (zeroing moved to a single hipMemsetAsync in the launcher).
__global__ void k_scatter(const int* __restrict__ src,
                          const int* __restrict__ dst,
                          int* __restrict__ cursor,
                          int2* __restrict__ spair, int E) {
  int e = blockIdx.x * 256 + threadIdx.x;
  if (e < E) {
    int s = src[e], d = dst[e];
    int p = atomicAdd(&cursor[d], 1);
    spair[p] = make_int2(s, d);
  }
}

// ---------------- node kernel (transposed MFMA) with fused scan1 -----------

__global__ __launch_bounds__(256) void k_node(
    const float* __restrict__ x, const unsigned short* __restrict__ wt,
    const float* __restrict__ b_in, const float* __restrict__ ln_g,
    const float* __restrict__ ln_b,
    unsigned short* __restrict__ qg, unsigned short* __restrict__ kg,
    unsigned short* __restrict__ vg,
    int N, const int* __restrict__ hist, int* __restrict__ incl,
    int* __restrict__ bsum, int nodeBlocks) {
  int t = threadIdx.x;

  // ---- fused scan1 blocks ----
  if ((int)blockIdx.x >= nodeBlocks) {
    __shared__ int sd[256];
    int bid = blockIdx.x - nodeBlocks;
    int base = bid * 1024 + t * 4;
    int v[4]; int ts = 0;
#pragma unroll
    for (int i = 0; i < 4; ++i) {
      int idx = base + i;
      v[i] = (idx < N) ? hist[idx] : 0;
      ts += v[i];
    }
    sd[t] = ts;
    __syncthreads();
    for (int off = 1; off < 256; off <<= 1) {
      int xv = (t >= off) ? sd[t - off] : 0;
      __syncthreads();
      sd[t] += xv;
      __syncthreads();
    }
    int run = sd[t] - ts;
#pragma unroll
    for (int i = 0; i < 4; ++i) {
      run += v[i];
      int idx = base + i;
      if (idx < N) incl[idx] = run;
    }
    if (t == 255) bsum[bid] = sd[255];
    return;
  }

  __shared__ __align__(16) unsigned short WALL[4 * 64 * 72];
  __shared__ __align__(16) unsigned short HT[64 * 72];   // h [node][ch]
  __shared__ __align__(16) float LNG[64], LNB[64], BIN[64];

  int lane = t & 63, wv = t >> 6;
  int nl = lane & 15, q = lane >> 4;
  int w16 = wv * 16;
  int n0g = blockIdx.x * 64;

  {
    const uint4* s4 = (const uint4*)wt;
    uint4* d4 = (uint4*)WALL;
#pragma unroll
    for (int i = 0; i < 9; ++i) d4[i * 256 + t] = s4[i * 256 + t];
  }
  if (t < 64) { LNG[t] = ln_g[t]; LNB[t] = ln_b[t]; BIN[t] = b_in[t]; }

  int row = n0g + w16 + nl;        // my node
  bf16x8 b[2];                     // B-frag: x[node=nl][k]
#pragma unroll
  for (int s = 0; s < 2; ++s) {
    union { unsigned int u[4]; bf16x8 v; } fb;
    if (row < N) {
      int kb = s * 32 + q * 8;
      float4 xa = *(const float4*)(x + (size_t)row * 64 + kb);
      float4 xb = *(const float4*)(x + (size_t)row * 64 + kb + 4);
      fb.u[0] = cvt_pk_bf16(xa.x, xa.y);
      fb.u[1] = cvt_pk_bf16(xa.z, xa.w);
      fb.u[2] = cvt_pk_bf16(xb.x, xb.y);
      fb.u[3] = cvt_pk_bf16(xb.z, xb.w);
    } else {
#pragma unroll
      for (int j = 0; j < 4; ++j) fb.u[j] = 0;
    }
    b[s] = fb.v;
  }
  __syncthreads();

  // GEMM1: h = relu(x @ W_in + b_in); lane holds ch m0*16+q*4+r of node nl
  f32x4 h[4];
#pragma unroll
  for (int m0 = 0; m0 < 4; ++m0) {
    f32x4 acc = *(const f32x4*)&BIN[m0 * 16 + q * 4];
    acc = __builtin_amdgcn_mfma_f32_16x16x32_bf16(
        ld_bf8(&WALL[(m0 * 16 + nl) * 72 + q * 8]), b[0], acc, 0, 0, 0);
    acc = __builtin_amdgcn_mfma_f32_16x16x32_bf16(
        ld_bf8(&WALL[(m0 * 16 + nl) * 72 + 32 + q * 8]), b[1], acc, 0, 0, 0);
#pragma unroll
    for (int r = 0; r < 4; ++r) acc[r] = fmaxf(acc[r], 0.f);
    h[m0] = acc;
  }

  // LayerNorm over channels of node nl: local 16 + reduce across q-lanes
  float sv = 0.f, sq = 0.f;
#pragma unroll
  for (int m0 = 0; m0 < 4; ++m0)
#pragma unroll
    for (int r = 0; r < 4; ++r) {
      float v = h[m0][r];
      sv += v; sq += v * v;
    }
  sv += __shfl_xor(sv, 16); sq += __shfl_xor(sq, 16);
  sv += __shfl_xor(sv, 32); sq += __shfl_xor(sq, 32);
  float mu = sv * (1.f / 64.f);
  float var = sq * (1.f / 64.f) - mu * mu;
  float rs = rsqrtf(var + 1e-5f);
#pragma unroll
  for (int m0 = 0; m0 < 4; ++m0) {
    f32x4 g4 = *(const f32x4*)&LNG[m0 * 16 + q * 4];
    f32x4 o4 = *(const f32x4*)&LNB[m0 * 16 + q * 4];
    float v0 = (h[m0][0] - mu) * rs * g4[0] + o4[0];
    float v1 = (h[m0][1] - mu) * rs * g4[1] + o4[1];
    float v2 = (h[m0][2] - mu) * rs * g4[2] + o4[2];
    float v3 = (h[m0][3] - mu) * rs * g4[3] + o4[3];
    uint2 pk;
    pk.x = cvt_pk_bf16(v0, v1);
    pk.y = cvt_pk_bf16(v2, v3);
    *(uint2*)&HT[(w16 + nl) * 72 + m0 * 16 + q * 4] = pk;
  }

  b[0] = ld_bf8(&HT[(w16 + nl) * 72 + q * 8]);
  b[1] = ld_bf8(&HT[(w16 + nl) * 72 + 32 + q * 8]);

  unsigned short* Og[3] = {qg, kg, vg};
  bool g = row < N;
#pragma unroll
  for (int m = 0; m < 3; ++m) {
    const unsigned short* Wm = WALL + (m + 1) * 4608;
#pragma unroll
    for (int m0 = 0; m0 < 4; ++m0) {
      f32x4 acc = {0.f, 0.f, 0.f, 0.f};
      acc = __builtin_amdgcn_mfma_f32_16x16x32_bf16(
          ld_bf8(&Wm[(m0 * 16 + nl) * 72 + q * 8]), b[0], acc, 0, 0, 0);
      acc = __builtin_amdgcn_mfma_f32_16x16x32_bf16(
          ld_bf8(&Wm[(m0 * 16 + nl) * 72 + 32 + q * 8]), b[1], acc, 0, 0, 0);
      if (g) {
        uint2 pk;
        pk.x = cvt_pk_bf16(acc[0], acc[1]);
        pk.y = cvt_pk_bf16(acc[2], acc[3]);
        // v (m==2) stored PERMUTED: pos(c)=q*16+m0*4+r so a k_edge lane
        // reads its 16 v-elems as one contiguous 32B block.  q/k unchanged.
        int off = (m == 2) ? (q * 16 + m0 * 4) : (m0 * 16 + q * 4);
        *(uint2*)(Og[m] + (size_t)row * 64 + off) = pk;
      }
    }
  }
}

// ---- edge kernel (persistent, 4 blocks/CU, R21 body, tile-range split) ----

__global__ __launch_bounds__(256, 4) void k_edge(
    const int2* __restrict__ spair, const float* __restrict__ pos,
    const unsigned short* __restrict__ qg, const unsigned short* __restrict__ kg,
    const unsigned short* __restrict__ vg,
    const unsigned short* __restrict__ wt,
    const float* __restrict__ pn_W1, const float* __restrict__ pn_b1,
    const float* __restrict__ pn_b2,
    const float* __restrict__ an_b1, const float* __restrict__ an_b2,
    float* __restrict__ sg, float* __restrict__ accg, int E,
    int tileLo, int tileHi) {
  __shared__ __align__(16) unsigned short WAB[2 * 64 * 72];  // pn_W2 | an_W1
  __shared__ __align__(16) unsigned short SD[64 * 72];   // delta, then pay
  __shared__ __align__(16) unsigned short SB[64 * 72];   // a1, then ex
  __shared__ float W1[3 * 64];
  __shared__ float B1[64];
  __shared__ __align__(16) float B2[64], AB1[64], AB2[64];

  int t = threadIdx.x;
  int lane = t & 63, wv = t >> 6;
  int nl = lane & 15, q = lane >> 4;
  int w16 = wv * 16;

  // ---- one-time staging: pn_W2 + an_W1 to LDS (uint4 memcpy) ----
  {
    const uint4* s4 = (const uint4*)(wt + 4 * 4608);  // matrices 4,5
    uint4* d4 = (uint4*)WAB;
#pragma unroll
    for (int i = 0; i < 5; ++i) {
      int idx = i * 256 + t;
      if (idx < 1152) d4[idx] = s4[idx];
    }
  }
  if (t < 192) W1[t] = pn_W1[t];
  if (t < 64) {
    B1[t] = pn_b1[t];  B2[t] = pn_b2[t];
    AB1[t] = an_b1[t]; AB2[t] = an_b2[t];
  }
  // ---- an_W2 A-frags -> registers (32 VGPR), straight from wt ----
  bf16x8 wan2r[8];
#pragma unroll
  for (int m0 = 0; m0 < 4; ++m0)
#pragma unroll
    for (int s = 0; s < 2; ++s)
      wan2r[m0 * 2 + s] =
          ld_bf8(wt + 6 * 4608 + (m0 * 16 + nl) * 72 + s * 32 + q * 8);
  const unsigned short* WPN2 = WAB;
  const unsigned short* WAN1 = WAB + 4608;
  __syncthreads();   // the ONLY barrier: weights/biases visible to all waves

  // Lane L of wave wv owns edge e0 + w16 + (L&15): its (src,dst) pair "my"
  // IS the tile's cross-lane state (distributed via __shfl, no LDS, no
  // barriers; SD/SB strips rows w16..w16+15 stay wave-private).
  long er_off = w16 + nl;
  int2 my;
  {
    long er = (long)(tileLo + blockIdx.x) * 64 + er_off;
    my = (er < E) ? spair[er] : make_int2(0, 0);
  }

  for (int tile = tileLo + blockIdx.x; tile < tileHi; tile += gridDim.x) {
    long e0 = (long)tile * 64;

    // ---- tile-top fan-out: all gathers issue off prefetched "my" ----
    const unsigned short* qr = qg + (size_t)my.y * 64;
    const unsigned short* kr = kg + (size_t)my.x * 64;
    bf16x8 qf[2], kf[2];
#pragma unroll
    for (int s = 0; s < 2; ++s) {
      int kb = s * 32 + q * 8;
      qf[s] = ld_bf8(qr + kb);
      kf[s] = ld_bf8(kr + kb);
    }
    // v for my OWN edge's src: PERMUTED layout -> one contiguous 32B
    const unsigned short* vr = vg + (size_t)my.x * 64;
    bf16x8 vlo = ld_bf8(vr + q * 16);
    bf16x8 vhi = ld_bf8(vr + q * 16 + 8);
    // pos diffs for my own edge (strip row w16+nl == my edge)
    float p0 = pos[my.y * 3 + 0] - pos[my.x * 3 + 0];
    float p1 = pos[my.y * 3 + 1] - pos[my.x * 3 + 1];
    float p2 = pos[my.y * 3 + 2] - pos[my.x * 3 + 2];

    // ---- prefetch next tile's spair into regs (hide under compute) ----
    int2 nxt = make_int2(0, 0);
    {
      long ntile = (long)tile + gridDim.x;
      if (ntile < tileHi) {
        long ner = ntile * 64 + er_off;
        nxt = (ner < E) ? spair[ner] : make_int2(0, 0);
      }
    }

    bool elive = (e0 + er_off) < E;   // my edge's liveness (col = nl)

    bf16x8 b[2];

    // ---- pos-MLP layer1 (K=3) straight into B-frag registers ----
#pragma unroll
    for (int s = 0; s < 2; ++s) {
      union { unsigned int u[4]; bf16x8 v; } fb;
      int kb = s * 32 + q * 8;
#pragma unroll
      for (int jj = 0; jj < 4; ++jj) {
        int c0 = kb + 2 * jj, c1 = c0 + 1;
        float v0 = fmaf(p0, W1[c0],
                   fmaf(p1, W1[64 + c0],
                   fmaf(p2, W1[128 + c0], B1[c0])));
        float v1 = fmaf(p0, W1[c1],
                   fmaf(p1, W1[64 + c1],
                   fmaf(p2, W1[128 + c1], B1[c1])));
        fb.u[jj] = cvt_pk_bf16(fmaxf(v0, 0.f), fmaxf(v1, 0.f));
      }
      b[s] = fb.v;
    }

    // ---- GEMM1: delta^T = pn_W2^T @ A1^T, bias-in-acc, relu -> SD ----
    f32x4 dlt[4];
#pragma unroll
    for (int m0 = 0; m0 < 4; ++m0) {
      f32x4 acc = *(const f32x4*)&B2[m0 * 16 + q * 4];
      acc = __builtin_amdgcn_mfma_f32_16x16x32_bf16(
          ld_bf8(&WPN2[(m0 * 16 + nl) * 72 + q * 8]), b[0], acc, 0, 0, 0);
      acc = __builtin_amdgcn_mfma_f32_16x16x32_bf16(
          ld_bf8(&WPN2[(m0 * 16 + nl) * 72 + 32 + q * 8]), b[1], acc, 0, 0, 0);
#pragma unroll
      for (int r = 0; r < 4; ++r) acc[r] = fmaxf(acc[r], 0.f);
      dlt[m0] = acc;
      uint2 pk;
      pk.x = cvt_pk_bf16(acc[0], acc[1]);
      pk.y = cvt_pk_bf16(acc[2], acc[3]);
      *(uint2*)&SD[(w16 + nl) * 72 + m0 * 16 + q * 4] = pk;
    }

    // ---- build ai = q[dst]-k[src]+delta in B-frag layout (reads SD) ----
#pragma unroll
    for (int s = 0; s < 2; ++s) {
      int kb = s * 32 + q * 8;
      bf16x8 d8 = ld_bf8(&SD[(w16 + nl) * 72 + kb]);
      union { unsigned int u[4]; bf16x8 v; } fb;
#pragma unroll
      for (int jj = 0; jj < 4; ++jj) {
        float v0 = (float)qf[s][2 * jj]     - (float)kf[s][2 * jj]     + (float)d8[2 * jj];
        float v1 = (float)qf[s][2 * jj + 1] - (float)kf[s][2 * jj + 1] + (float)d8[2 * jj + 1];
        fb.u[jj] = cvt_pk_bf16(v0, v1);
      }
      b[s] = fb.v;
    }

    // ---- overwrite SD with pay = delta + v[src]  (same-wave DS order) ----
#pragma unroll
    for (int m0 = 0; m0 < 4; ++m0) {
      float va0, va1, va2, va3;
      if (m0 == 0)      { va0 = (float)vlo[0]; va1 = (float)vlo[1];
                          va2 = (float)vlo[2]; va3 = (float)vlo[3]; }
      else if (m0 == 1) { va0 = (float)vlo[4]; va1 = (float)vlo[5];
                          va2 = (float)vlo[6]; va3 = (float)vlo[7]; }
      else if (m0 == 2) { va0 = (float)vhi[0]; va1 = (float)vhi[1];
                          va2 = (float)vhi[2]; va3 = (float)vhi[3]; }
      else              { va0 = (float)vhi[4]; va1 = (float)vhi[5];
                          va2 = (float)vhi[6]; va3 = (float)vhi[7]; }
      uint2 pk;
      pk.x = cvt_pk_bf16(dlt[m0][0] + va0, dlt[m0][1] + va1);
      pk.y = cvt_pk_bf16(dlt[m0][2] + va2, dlt[m0][3] + va3);
      *(uint2*)&SD[(w16 + nl) * 72 + m0 * 16 + q * 4] = pk;
    }

    // ---- GEMM2: a1^T = an_W1^T @ ai^T, bias-in-acc, relu -> SB ----
#pragma unroll
    for (int m0 = 0; m0 < 4; ++m0) {
      f32x4 acc = *(const f32x4*)&AB1[m0 * 16 + q * 4];
      acc = __builtin_amdgcn_mfma_f32_16x16x32_bf16(
          ld_bf8(&WAN1[(m0 * 16 + nl) * 72 + q * 8]), b[0], acc, 0, 0, 0);
      acc = __builtin_amdgcn_mfma_f32_16x16x32_bf16(
          ld_bf8(&WAN1[(m0 * 16 + nl) * 72 + 32 + q * 8]), b[1], acc, 0, 0, 0);
      uint2 pk;
      pk.x = cvt_pk_bf16(fmaxf(acc[0], 0.f), fmaxf(acc[1], 0.f));
      pk.y = cvt_pk_bf16(fmaxf(acc[2], 0.f), fmaxf(acc[3], 0.f));
      *(uint2*)&SB[(w16 + nl) * 72 + m0 * 16 + q * 4] = pk;
    }

    // ---- GEMM3: alpha^T = an_W2^T(regs) @ a1^T; ex = exp(relu) -> SB ----
    b[0] = ld_bf8(&SB[(w16 + nl) * 72 + q * 8]);
    b[1] = ld_bf8(&SB[(w16 + nl) * 72 + 32 + q * 8]);
#pragma unroll
    for (int m0 = 0; m0 < 4; ++m0) {
      f32x4 acc = *(const f32x4*)&AB2[m0 * 16 + q * 4];
      acc = __builtin_amdgcn_mfma_f32_16x16x32_bf16(
          wan2r[m0 * 2 + 0], b[0], acc, 0, 0, 0);
      acc = __builtin_amdgcn_mfma_f32_16x16x32_bf16(
          wan2r[m0 * 2 + 1], b[1], acc, 0, 0, 0);
      float e0v = elive ? __expf(fmaxf(acc[0], 0.f)) : 0.f;
      float e1v = elive ? __expf(fmaxf(acc[1], 0.f)) : 0.f;
      float e2v = elive ? __expf(fmaxf(acc[2], 0.f)) : 0.f;
      float e3v = elive ? __expf(fmaxf(acc[3], 0.f)) : 0.f;
      uint2 pk;
      pk.x = cvt_pk_bf16(e0v, e1v);
      pk.y = cvt_pk_bf16(e2v, e3v);
      *(uint2*)&SB[(w16 + nl) * 72 + m0 * 16 + q * 4] = pk;
    }

    // ---- segmented per-dst-run reduction (dst runs via shuffle) ----
    {
      int c = lane;
      int cur = __shfl(my.y, 0);
      float ssum = 0.f, asum = 0.f;
#pragma unroll
      for (int i = 0; i < 16; ++i) {
        int d = __shfl(my.y, i);
        if (d != cur) {
          if (ssum != 0.f) {
            atomicAdd(&sg[(size_t)cur * 64 + c], ssum);
            atomicAdd(&accg[(size_t)cur * 64 + c], asum);
          }
          cur = d; ssum = 0.f; asum = 0.f;
        }
        float ex = bf2f(SB[(w16 + i) * 72 + c]);
        float pay = bf2f(SD[(w16 + i) * 72 + c]);   // pay = delta + v
        ssum += ex;
        asum = fmaf(ex, pay, asum);
      }
      if (ssum != 0.f) {
        atomicAdd(&sg[(size_t)cur * 64 + c], ssum);
        atomicAdd(&accg[(size_t)cur * 64 + c], asum);
      }
    }

    my = nxt;   // rotate prefetched pair
  }
}

// ------------------------- out kernel (transposed MFMA) --------------------

__global__ __launch_bounds__(256) void k_out(const float* __restrict__ accg,
                                             const float* __restrict__ sg,
                                             const unsigned short* __restrict__ wt,
                                             const float* __restrict__ b,
                                             float* __restrict__ out, int N) {
  __shared__ __align__(16) unsigned short WO[64 * 72];
  __shared__ __align__(16) float BO[64];
  int t = threadIdx.x;
  int lane = t & 63, wv = t >> 6;
  int nl = lane & 15, q = lane >> 4;
  int w16 = wv * 16;
  int n0g = blockIdx.x * 64;

  {
    const uint4* s4 = (const uint4*)(wt + 7 * 4608);  // matrix 7 = W_out
    uint4* d4 = (uint4*)WO;
#pragma unroll
    for (int i = 0; i < 3; ++i) {
      int idx = i * 256 + t;
      if (idx < 576) d4[idx] = s4[idx];
    }
  }
  if (t < 64) BO[t] = b[t];

  int row = n0g + w16 + nl;        // my node
  bf16x8 bb[2];
#pragma unroll
  for (int s = 0; s < 2; ++s) {
    union { unsigned int u[4]; bf16x8 v; } fb;
    if (row < N) {
      int kb = s * 32 + q * 8;
      float4 na = *(const float4*)(accg + (size_t)row * 64 + kb);
      float4 nb = *(const float4*)(accg + (size_t)row * 64 + kb + 4);
      float4 da = *(const float4*)(sg + (size_t)row * 64 + kb);
      float4 db = *(const float4*)(sg + (size_t)row * 64 + kb + 4);
      fb.u[0] = cvt_pk_bf16(na.x / (da.x + 1e-16f), na.y / (da.y + 1e-16f));
      fb.u[1] = cvt_pk_bf16(na.z / (da.z + 1e-16f), na.w / (da.w + 1e-16f));
      fb.u[2] = cvt_pk_bf16(nb.x / (db.x + 1e-16f), nb.y / (db.y + 1e-16f));
      fb.u[3] = cvt_pk_bf16(nb.z / (db.z + 1e-16f), nb.w / (db.w + 1e-16f));
    } else {
#pragma unroll
      for (int j = 0; j < 4; ++j) fb.u[j] = 0;
    }
    bb[s] = fb.v;
  }
  __syncthreads();

  bool g = row < N;
#pragma unroll
  for (int m0 = 0; m0 < 4; ++m0) {
    f32x4 acc = *(const f32x4*)&BO[m0 * 16 + q * 4];
    acc = __builtin_amdgcn_mfma_f32_16x16x32_bf16(
        ld_bf8(&WO[(m0 * 16 + nl) * 72 + q * 8]), bb[0], acc, 0, 0, 0);
    acc = __builtin_amdgcn_mfma_f32_16x16x32_bf16(
        ld_bf8(&WO[(m0 * 16 + nl) * 72 + 32 + q * 8]), bb[1], acc, 0, 0, 0);
    if (g) {
      float4 o;
      o.x = fmaxf(acc[0], 0.f);
      o.y = fmaxf(acc[1], 0.f);
      o.z = fmaxf(acc[2], 0.f);
      o.w = fmaxf(acc[3], 0.f);
      *(float4*)(out + (size_t)row * 64 + m0 * 16 + q * 4) = o;
    }
  }
}

// ------------------------------- launcher ----------------------------------

extern "C" void kernel_launch(void* const* d_in, const int* in_sizes, int n_in,
                              void* d_out, int out_size, void* d_ws, size_t ws_size,
                              hipStream_t stream) {
  const float* x     = (const float*)d_in[0];
  const float* pos   = (const float*)d_in[1];
  const int*   eidx  = (const int*)d_in[2];
  const float* W_in  = (const float*)d_in[3];
  const float* b_in  = (const float*)d_in[4];
  const float* ln_g  = (const float*)d_in[5];
  const float* ln_b  = (const float*)d_in[6];
  const float* W_lin = (const float*)d_in[7];
  const float* W_src = (const float*)d_in[8];
  const float* W_dst = (const float*)d_in[9];
  const float* pn_W1 = (const float*)d_in[10];
  const float* pn_b1 = (const float*)d_in[11];
  const float* pn_W2 = (const float*)d_in[12];
  const float* pn_b2 = (const float*)d_in[13];
  const float* an_W1 = (const float*)d_in[14];
  const float* an_b1 = (const float*)d_in[15];
  const float* an_W2 = (const float*)d_in[16];
  const float* an_b2 = (const float*)d_in[17];
  const float* W_out = (const float*)d_in[18];
  const float* b_out = (const float*)d_in[19];
  float* out = (float*)d_out;

  int N = in_sizes[0] / 64;
  int E = in_sizes[2] / 2;
  const int* src = eidx;
  const int* dst = eidx + E;

  char* w = (char*)d_ws;
  auto alloc = [&](size_t bytes) -> void* {
    void* p = (void*)w;
    w += (bytes + 255) & ~(size_t)255;
    return p;
  };
  unsigned short* qg = (unsigned short*)alloc((size_t)N * 64 * 2);
  unsigned short* kg = (unsigned short*)alloc((size_t)N * 64 * 2);
  unsigned short* vg = (unsigned short*)alloc((size_t)N * 64 * 2);
  float* sg   = (float*)alloc((size_t)N * 64 * 4);
  float* accg = (float*)alloc((size_t)N * 64 * 4);   // contiguous after sg
  int2* spair = (int2*)alloc((size_t)E * 8);
  unsigned short* wt = (unsigned short*)alloc(8 * 4608 * 2);
  int* hist   = (int*)alloc((size_t)N * 4);
  int* cursor = (int*)alloc((size_t)N * 4);
  int* bsum   = (int*)alloc(1024 * 4);
  int* incl   = (int*)spair;  // scan scratch aliased into spair (dead before
                              // k_scatter writes spair; k_scan3 reads first)

  int nb1 = (N + 1023) / 1024;               // <= 256 required by k_scan3
  int nodeBlocks = (N + 63) / 64;
  int histBlocks = (E + 255) / 256;
  int numTiles = (E + 63) / 64;
  int tileMid = numTiles / 2;
  int grid1 = tileMid < 1024 ? (tileMid > 0 ? tileMid : 1) : 1024;
  int grid2 = (numTiles - tileMid) < 1024 ? (numTiles - tileMid) : 1024;

  // sg+accg are contiguous: one memset covers both (zero before k_edge).
  hipMemsetAsync(sg, 0, (size_t)N * 64 * 4 * 2, stream);
  hipMemsetAsync(hist, 0, (size_t)N * 4, stream);
  k_prep_hist<<<8 + histBlocks, 256, 0, stream>>>(
      W_in, W_dst, W_src, W_lin, pn_W2, an_W1, an_W2, W_out, wt, dst, hist, E);
  k_node<<<nodeBlocks + nb1, 256, 0, stream>>>(
      x, wt, b_in, ln_g, ln_b, qg, kg, vg, N, hist, incl, bsum, nodeBlocks);
  k_scan3<<<nb1, 256, 0, stream>>>(incl, hist, bsum, cursor, N);
  k_scatter<<<histBlocks, 256, 0, stream>>>(src, dst, cursor, spair, E);
  k_edge<<<grid1, 256, 0, stream>>>(spair, pos, qg, kg, vg, wt,
                                    pn_W1, pn_b1, pn_b2, an_b1, an_b2,
                                    sg, accg, E, 0, tileMid);
  k_edge<<<grid2, 256, 0, stream>>>(spair, pos, qg, kg, vg, wt,
                                    pn_W1, pn_b1, pn_b2, an_b1, an_b2,
                                    sg, accg, E, tileMid, numTiles);
  k_out<<<nodeBlocks, 256, 0, stream>>>(accg, sg, wt, b_out, out, N);
}

// Round 11
// 505.899 us; speedup vs baseline: 1.0286x; 1.0286x over previous
//
#include <hip/hip_runtime.h>

// ---------------------------------------------------------------------------
// PointTransformerBlock, MI355X.  R23 = R21 (best passing, 497us) + atomic-
// window overlap; k_edge body UNTOUCHED:
//  R22's split revealed the tail: counting-sort = 2 passes of 1.6M random
//  device-scope atomics @ ~12G atomics/s (k_scatter 134us, VALU 0.3%;
//  prep_hist's hist ~130us by budget).  ~265us = 53% of runtime.
//  - HIST FUSED INTO k_node's dispatch as sibling blocks: k_node's ~30us of
//    MFMA work now runs INSIDE hist's atomic-bound window (0.3% VALU = idle
//    CUs).  prep becomes 8-block weights-only; scan1 is its own tiny kernel.
//  - R22 regressions reverted: single k_edge dispatch (no drain bubble),
//    scatter re-fused with sg/accg zeroing (zero writes overlap atomics).
//  - R21 k_edge kept verbatim: v-permute 32B gather, transposed GEMMs,
//    an_W2 in regs, pay-fused SD, reg tile state, zero per-tile barriers,
//    launch_bounds(256,4), LDS 38.9KB.
//  MFMA layouts (HW-verified, guide §3): A[m=lane&15][k=q*8+j],
//  B[k=q*8+j][n=lane&15], C/D col=lane&15 row=q*4+r.
// ---------------------------------------------------------------------------

typedef __bf16 bf16x8 __attribute__((ext_vector_type(8)));
typedef float f32x4 __attribute__((ext_vector_type(4)));

__device__ inline unsigned short f2bf(float f) {
  return __builtin_bit_cast(unsigned short, (__bf16)f);   // v_cvt (RNE)
}
__device__ inline float bf2f(unsigned short s) {
  return __uint_as_float(((unsigned int)s) << 16);
}
__device__ inline bf16x8 ld_bf8(const unsigned short* p) {
  union { uint4 i; bf16x8 v; } u;
  u.i = *(const uint4*)p;
  return u.v;
}
// packed f32->2xbf16 (gfx950; no builtin -- guide T12/m240). dst.lo=cvt(lo).
__device__ inline unsigned int cvt_pk_bf16(float lo, float hi) {
  unsigned int r;
  asm("v_cvt_pk_bf16_f32 %0, %1, %2" : "=v"(r) : "v"(lo), "v"(hi));
  return r;
}

// --------------------- prep kernel (weights only, 8 blocks) ----------------

__global__ __launch_bounds__(256) void k_prep(
    const float* __restrict__ W_in, const float* __restrict__ W_dst,
    const float* __restrict__ W_src, const float* __restrict__ W_lin,
    const float* __restrict__ pn_W2, const float* __restrict__ an_W1,
    const float* __restrict__ an_W2, const float* __restrict__ W_out,
    unsigned short* __restrict__ wt) {
  int t = threadIdx.x;
  const float* Ws[8] = {W_in, W_dst, W_src, W_lin, pn_W2, an_W1, an_W2, W_out};
  const float* W = Ws[blockIdx.x];
  unsigned short* o = wt + (size_t)blockIdx.x * 4608;
#pragma unroll
  for (int i = 0; i < 16; ++i) {
    int e = i * 256 + t;           // e = k*64 + n  (coalesced read)
    int k = e >> 6, n = e & 63;
    o[n * 72 + k] = f2bf(W[e]);    // wt[n][k] = W^T[n][k]
  }
}

// ------------------------------ sort kernels -------------------------------

// scan1: per-1024-chunk inclusive scan of hist -> incl, chunk sums -> bsum.
__global__ __launch_bounds__(256) void k_scan1(
    const int* __restrict__ hist, int* __restrict__ incl,
    int* __restrict__ bsum, int N) {
  __shared__ int sd[256];
  int t = threadIdx.x;
  int base = blockIdx.x * 1024 + t * 4;
  int v[4]; int ts = 0;
#pragma unroll
  for (int i = 0; i < 4; ++i) {
    int idx = base + i;
    v[i] = (idx < N) ? hist[idx] : 0;
    ts += v[i];
  }
  sd[t] = ts;
  __syncthreads();
  for (int off = 1; off < 256; off <<= 1) {
    int xv = (t >= off) ? sd[t - off] : 0;
    __syncthreads();
    sd[t] += xv;
    __syncthreads();
  }
  int run = sd[t] - ts;
#pragma unroll
  for (int i = 0; i < 4; ++i) {
    run += v[i];
    int idx = base + i;
    if (idx < N) incl[idx] = run;
  }
  if (t == 255) bsum[blockIdx.x] = sd[255];
}

// scan3 with inline block-offset: reduce bsum[0..blockIdx) in-block.
// Requires gridDim <= 256 (N <= 262144).
__global__ __launch_bounds__(256) void k_scan3(
    const int* __restrict__ incl, const int* __restrict__ hist,
    const int* __restrict__ bsum, int* __restrict__ cursor, int N) {
  __shared__ int red[256];
  int t = threadIdx.x;
  red[t] = (t < (int)blockIdx.x) ? bsum[t] : 0;
  __syncthreads();
#pragma unroll
  for (int off = 128; off; off >>= 1) {
    if (t < off) red[t] += red[t + off];
    __syncthreads();
  }
  int bo = red[0];
  int base = blockIdx.x * 1024 + t * 4;
#pragma unroll
  for (int i = 0; i < 4; ++i) {
    int id = base + i;
    if (id < N) cursor[id] = bo + incl[id] - hist[id];
  }
}

// scatter with fused sg/accg zeroing (sibling blocks; zero writes overlap
// the atomic-bound scatter blocks' idle memory slots).
__global__ void k_scatter_zero(const int* __restrict__ src,
                               const int* __restrict__ dst,
                               int* __restrict__ cursor,
                               int2* __restrict__ spair, int E,
                               float4* __restrict__ zbase, int zcount,
                               int scatterBlocks) {
  int t = threadIdx.x;
  if ((int)blockIdx.x >= scatterBlocks) {
    int i = ((int)blockIdx.x - scatterBlocks) * 256 + t;
    if (i < zcount) zbase[i] = make_float4(0.f, 0.f, 0.f, 0.f);
    return;
  }
  int e = blockIdx.x * 256 + t;
  if (e < E) {
    int s = src[e], d = dst[e];
    int p = atomicAdd(&cursor[d], 1);
    spair[p] = make_int2(s, d);
  }
}

// -------- node kernel (transposed MFMA) with FUSED histogram blocks -------

__global__ __launch_bounds__(256) void k_node_hist(
    const float* __restrict__ x, const unsigned short* __restrict__ wt,
    const float* __restrict__ b_in, const float* __restrict__ ln_g,
    const float* __restrict__ ln_b,
    unsigned short* __restrict__ qg, unsigned short* __restrict__ kg,
    unsigned short* __restrict__ vg,
    int N, const int* __restrict__ dst, int* __restrict__ hist, int E,
    int nodeBlocks) {
  int t = threadIdx.x;

  // ---- fused histogram blocks (atomic-bound; overlap node MFMA work) ----
  if ((int)blockIdx.x >= nodeBlocks) {
    int e = ((int)blockIdx.x - nodeBlocks) * 256 + t;
    if (e < E) atomicAdd(&hist[dst[e]], 1);
    return;
  }

  __shared__ __align__(16) unsigned short WALL[4 * 64 * 72];
  __shared__ __align__(16) unsigned short HT[64 * 72];   // h [node][ch]
  __shared__ __align__(16) float LNG[64], LNB[64], BIN[64];

  int lane = t & 63, wv = t >> 6;
  int nl = lane & 15, q = lane >> 4;
  int w16 = wv * 16;
  int n0g = blockIdx.x * 64;

  {
    const uint4* s4 = (const uint4*)wt;
    uint4* d4 = (uint4*)WALL;
#pragma unroll
    for (int i = 0; i < 9; ++i) d4[i * 256 + t] = s4[i * 256 + t];
  }
  if (t < 64) { LNG[t] = ln_g[t]; LNB[t] = ln_b[t]; BIN[t] = b_in[t]; }

  int row = n0g + w16 + nl;        // my node
  bf16x8 b[2];                     // B-frag: x[node=nl][k]
#pragma unroll
  for (int s = 0; s < 2; ++s) {
    union { unsigned int u[4]; bf16x8 v; } fb;
    if (row < N) {
      int kb = s * 32 + q * 8;
      float4 xa = *(const float4*)(x + (size_t)row * 64 + kb);
      float4 xb = *(const float4*)(x + (size_t)row * 64 + kb + 4);
      fb.u[0] = cvt_pk_bf16(xa.x, xa.y);
      fb.u[1] = cvt_pk_bf16(xa.z, xa.w);
      fb.u[2] = cvt_pk_bf16(xb.x, xb.y);
      fb.u[3] = cvt_pk_bf16(xb.z, xb.w);
    } else {
#pragma unroll
      for (int j = 0; j < 4; ++j) fb.u[j] = 0;
    }
    b[s] = fb.v;
  }
  __syncthreads();

  // GEMM1: h = relu(x @ W_in + b_in); lane holds ch m0*16+q*4+r of node nl
  f32x4 h[4];
#pragma unroll
  for (int m0 = 0; m0 < 4; ++m0) {
    f32x4 acc = *(const f32x4*)&BIN[m0 * 16 + q * 4];
    acc = __builtin_amdgcn_mfma_f32_16x16x32_bf16(
        ld_bf8(&WALL[(m0 * 16 + nl) * 72 + q * 8]), b[0], acc, 0, 0, 0);
    acc = __builtin_amdgcn_mfma_f32_16x16x32_bf16(
        ld_bf8(&WALL[(m0 * 16 + nl) * 72 + 32 + q * 8]), b[1], acc, 0, 0, 0);
#pragma unroll
    for (int r = 0; r < 4; ++r) acc[r] = fmaxf(acc[r], 0.f);
    h[m0] = acc;
  }

  // LayerNorm over channels of node nl: local 16 + reduce across q-lanes
  float sv = 0.f, sq = 0.f;
#pragma unroll
  for (int m0 = 0; m0 < 4; ++m0)
#pragma unroll
    for (int r = 0; r < 4; ++r) {
      float v = h[m0][r];
      sv += v; sq += v * v;
    }
  sv += __shfl_xor(sv, 16); sq += __shfl_xor(sq, 16);
  sv += __shfl_xor(sv, 32); sq += __shfl_xor(sq, 32);
  float mu = sv * (1.f / 64.f);
  float var = sq * (1.f / 64.f) - mu * mu;
  float rs = rsqrtf(var + 1e-5f);
#pragma unroll
  for (int m0 = 0; m0 < 4; ++m0) {
    f32x4 g4 = *(const f32x4*)&LNG[m0 * 16 + q * 4];
    f32x4 o4 = *(const f32x4*)&LNB[m0 * 16 + q * 4];
    float v0 = (h[m0][0] - mu) * rs * g4[0] + o4[0];
    float v1 = (h[m0][1] - mu) * rs * g4[1] + o4[1];
    float v2 = (h[m0][2] - mu) * rs * g4[2] + o4[2];
    float v3 = (h[m0][3] - mu) * rs * g4[3] + o4[3];
    uint2 pk;
    pk.x = cvt_pk_bf16(v0, v1);
    pk.y = cvt_pk_bf16(v2, v3);
    *(uint2*)&HT[(w16 + nl) * 72 + m0 * 16 + q * 4] = pk;
  }

  b[0] = ld_bf8(&HT[(w16 + nl) * 72 + q * 8]);
  b[1] = ld_bf8(&HT[(w16 + nl) * 72 + 32 + q * 8]);

  unsigned short* Og[3] = {qg, kg, vg};
  bool g = row < N;
#pragma unroll
  for (int m = 0; m < 3; ++m) {
    const unsigned short* Wm = WALL + (m + 1) * 4608;
#pragma unroll
    for (int m0 = 0; m0 < 4; ++m0) {
      f32x4 acc = {0.f, 0.f, 0.f, 0.f};
      acc = __builtin_amdgcn_mfma_f32_16x16x32_bf16(
          ld_bf8(&Wm[(m0 * 16 + nl) * 72 + q * 8]), b[0], acc, 0, 0, 0);
      acc = __builtin_amdgcn_mfma_f32_16x16x32_bf16(
          ld_bf8(&Wm[(m0 * 16 + nl) * 72 + 32 + q * 8]), b[1], acc, 0, 0, 0);
      if (g) {
        uint2 pk;
        pk.x = cvt_pk_bf16(acc[0], acc[1]);
        pk.y = cvt_pk_bf16(acc[2], acc[3]);
        // v (m==2) stored PERMUTED: pos(c)=q*16+m0*4+r so a k_edge lane
        // reads its 16 v-elems as one contiguous 32B block.  q/k unchanged.
        int off = (m == 2) ? (q * 16 + m0 * 4) : (m0 * 16 + q * 4);
        *(uint2*)(Og[m] + (size_t)row * 64 + off) = pk;
      }
    }
  }
}

// ---- edge kernel (persistent, 4 blocks/CU, R21 body verbatim) -------------

__global__ __launch_bounds__(256, 4) void k_edge(
    const int2* __restrict__ spair, const float* __restrict__ pos,
    const unsigned short* __restrict__ qg, const unsigned short* __restrict__ kg,
    const unsigned short* __restrict__ vg,
    const unsigned short* __restrict__ wt,
    const float* __restrict__ pn_W1, const float* __restrict__ pn_b1,
    const float* __restrict__ pn_b2,
    const float* __restrict__ an_b1, const float* __restrict__ an_b2,
    float* __restrict__ sg, float* __restrict__ accg, int E, int numTiles) {
  __shared__ __align__(16) unsigned short WAB[2 * 64 * 72];  // pn_W2 | an_W1
  __shared__ __align__(16) unsigned short SD[64 * 72];   // delta, then pay
  __shared__ __align__(16) unsigned short SB[64 * 72];   // a1, then ex
  __shared__ float W1[3 * 64];
  __shared__ float B1[64];
  __shared__ __align__(16) float B2[64], AB1[64], AB2[64];

  int t = threadIdx.x;
  int lane = t & 63, wv = t >> 6;
  int nl = lane & 15, q = lane >> 4;
  int w16 = wv * 16;

  // ---- one-time staging: pn_W2 + an_W1 to LDS (uint4 memcpy) ----
  {
    const uint4* s4 = (const uint4*)(wt + 4 * 4608);  // matrices 4,5
    uint4* d4 = (uint4*)WAB;
#pragma unroll
    for (int i = 0; i < 5; ++i) {
      int idx = i * 256 + t;
      if (idx < 1152) d4[idx] = s4[idx];
    }
  }
  if (t < 192) W1[t] = pn_W1[t];
  if (t < 64) {
    B1[t] = pn_b1[t];  B2[t] = pn_b2[t];
    AB1[t] = an_b1[t]; AB2[t] = an_b2[t];
  }
  // ---- an_W2 A-frags -> registers (32 VGPR), straight from wt ----
  bf16x8 wan2r[8];
#pragma unroll
  for (int m0 = 0; m0 < 4; ++m0)
#pragma unroll
    for (int s = 0; s < 2; ++s)
      wan2r[m0 * 2 + s] =
          ld_bf8(wt + 6 * 4608 + (m0 * 16 + nl) * 72 + s * 32 + q * 8);
  const unsigned short* WPN2 = WAB;
  const unsigned short* WAN1 = WAB + 4608;
  __syncthreads();   // the ONLY barrier: weights/biases visible to all waves

  // Lane L of wave wv owns edge e0 + w16 + (L&15): its (src,dst) pair "my"
  // IS the tile's cross-lane state (distributed via __shfl, no LDS, no
  // barriers; SD/SB strips rows w16..w16+15 stay wave-private).
  long er_off = w16 + nl;
  int2 my;
  {
    long er = (long)blockIdx.x * 64 + er_off;
    my = (er < E) ? spair[er] : make_int2(0, 0);
  }

  for (int tile = blockIdx.x; tile < numTiles; tile += gridDim.x) {
    long e0 = (long)tile * 64;

    // ---- tile-top fan-out: all gathers issue off prefetched "my" ----
    const unsigned short* qr = qg + (size_t)my.y * 64;
    const unsigned short* kr = kg + (size_t)my.x * 64;
    bf16x8 qf[2], kf[2];
#pragma unroll
    for (int s = 0; s < 2; ++s) {
      int kb = s * 32 + q * 8;
      qf[s] = ld_bf8(qr + kb);
      kf[s] = ld_bf8(kr + kb);
    }
    // v for my OWN edge's src: PERMUTED layout -> one contiguous 32B
    const unsigned short* vr = vg + (size_t)my.x * 64;
    bf16x8 vlo = ld_bf8(vr + q * 16);
    bf16x8 vhi = ld_bf8(vr + q * 16 + 8);
    // pos diffs for my own edge (strip row w16+nl == my edge)
    float p0 = pos[my.y * 3 + 0] - pos[my.x * 3 + 0];
    float p1 = pos[my.y * 3 + 1] - pos[my.x * 3 + 1];
    float p2 = pos[my.y * 3 + 2] - pos[my.x * 3 + 2];

    // ---- prefetch next tile's spair into regs (hide under compute) ----
    int2 nxt = make_int2(0, 0);
    {
      long ntile = (long)tile + gridDim.x;
      if (ntile < numTiles) {
        long ner = ntile * 64 + er_off;
        nxt = (ner < E) ? spair[ner] : make_int2(0, 0);
      }
    }

    bool elive = (e0 + er_off) < E;   // my edge's liveness (col = nl)

    bf16x8 b[2];

    // ---- pos-MLP layer1 (K=3) straight into B-frag registers ----
#pragma unroll
    for (int s = 0; s < 2; ++s) {
      union { unsigned int u[4]; bf16x8 v; } fb;
      int kb = s * 32 + q * 8;
#pragma unroll
      for (int jj = 0; jj < 4; ++jj) {
        int c0 = kb + 2 * jj, c1 = c0 + 1;
        float v0 = fmaf(p0, W1[c0],
                   fmaf(p1, W1[64 + c0],
                   fmaf(p2, W1[128 + c0], B1[c0])));
        float v1 = fmaf(p0, W1[c1],
                   fmaf(p1, W1[64 + c1],
                   fmaf(p2, W1[128 + c1], B1[c1])));
        fb.u[jj] = cvt_pk_bf16(fmaxf(v0, 0.f), fmaxf(v1, 0.f));
      }
      b[s] = fb.v;
    }

    // ---- GEMM1: delta^T = pn_W2^T @ A1^T, bias-in-acc, relu -> SD ----
    f32x4 dlt[4];
#pragma unroll
    for (int m0 = 0; m0 < 4; ++m0) {
      f32x4 acc = *(const f32x4*)&B2[m0 * 16 + q * 4];
      acc = __builtin_amdgcn_mfma_f32_16x16x32_bf16(
          ld_bf8(&WPN2[(m0 * 16 + nl) * 72 + q * 8]), b[0], acc, 0, 0, 0);
      acc = __builtin_amdgcn_mfma_f32_16x16x32_bf16(
          ld_bf8(&WPN2[(m0 * 16 + nl) * 72 + 32 + q * 8]), b[1], acc, 0, 0, 0);
#pragma unroll
      for (int r = 0; r < 4; ++r) acc[r] = fmaxf(acc[r], 0.f);
      dlt[m0] = acc;
      uint2 pk;
      pk.x = cvt_pk_bf16(acc[0], acc[1]);
      pk.y = cvt_pk_bf16(acc[2], acc[3]);
      *(uint2*)&SD[(w16 + nl) * 72 + m0 * 16 + q * 4] = pk;
    }

    // ---- build ai = q[dst]-k[src]+delta in B-frag layout (reads SD) ----
#pragma unroll
    for (int s = 0; s < 2; ++s) {
      int kb = s * 32 + q * 8;
      bf16x8 d8 = ld_bf8(&SD[(w16 + nl) * 72 + kb]);
      union { unsigned int u[4]; bf16x8 v; } fb;
#pragma unroll
      for (int jj = 0; jj < 4; ++jj) {
        float v0 = (float)qf[s][2 * jj]     - (float)kf[s][2 * jj]     + (float)d8[2 * jj];
        float v1 = (float)qf[s][2 * jj + 1] - (float)kf[s][2 * jj + 1] + (float)d8[2 * jj + 1];
        fb.u[jj] = cvt_pk_bf16(v0, v1);
      }
      b[s] = fb.v;
    }

    // ---- overwrite SD with pay = delta + v[src]  (same-wave DS order) ----
#pragma unroll
    for (int m0 = 0; m0 < 4; ++m0) {
      float va0, va1, va2, va3;
      if (m0 == 0)      { va0 = (float)vlo[0]; va1 = (float)vlo[1];
                          va2 = (float)vlo[2]; va3 = (float)vlo[3]; }
      else if (m0 == 1) { va0 = (float)vlo[4]; va1 = (float)vlo[5];
                          va2 = (float)vlo[6]; va3 = (float)vlo[7]; }
      else if (m0 == 2) { va0 = (float)vhi[0]; va1 = (float)vhi[1];
                          va2 = (float)vhi[2]; va3 = (float)vhi[3]; }
      else              { va0 = (float)vhi[4]; va1 = (float)vhi[5];
                          va2 = (float)vhi[6]; va3 = (float)vhi[7]; }
      uint2 pk;
      pk.x = cvt_pk_bf16(dlt[m0][0] + va0, dlt[m0][1] + va1);
      pk.y = cvt_pk_bf16(dlt[m0][2] + va2, dlt[m0][3] + va3);
      *(uint2*)&SD[(w16 + nl) * 72 + m0 * 16 + q * 4] = pk;
    }

    // ---- GEMM2: a1^T = an_W1^T @ ai^T, bias-in-acc, relu -> SB ----
#pragma unroll
    for (int m0 = 0; m0 < 4; ++m0) {
      f32x4 acc = *(const f32x4*)&AB1[m0 * 16 + q * 4];
      acc = __builtin_amdgcn_mfma_f32_16x16x32_bf16(
          ld_bf8(&WAN1[(m0 * 16 + nl) * 72 + q * 8]), b[0], acc, 0, 0, 0);
      acc = __builtin_amdgcn_mfma_f32_16x16x32_bf16(
          ld_bf8(&WAN1[(m0 * 16 + nl) * 72 + 32 + q * 8]), b[1], acc, 0, 0, 0);
      uint2 pk;
      pk.x = cvt_pk_bf16(fmaxf(acc[0], 0.f), fmaxf(acc[1], 0.f));
      pk.y = cvt_pk_bf16(fmaxf(acc[2], 0.f), fmaxf(acc[3], 0.f));
      *(uint2*)&SB[(w16 + nl) * 72 + m0 * 16 + q * 4] = pk;
    }

    // ---- GEMM3: alpha^T = an_W2^T(regs) @ a1^T; ex = exp(relu) -> SB ----
    b[0] = ld_bf8(&SB[(w16 + nl) * 72 + q * 8]);
    b[1] = ld_bf8(&SB[(w16 + nl) * 72 + 32 + q * 8]);
#pragma unroll
    for (int m0 = 0; m0 < 4; ++m0) {
      f32x4 acc = *(const f32x4*)&AB2[m0 * 16 + q * 4];
      acc = __builtin_amdgcn_mfma_f32_16x16x32_bf16(
          wan2r[m0 * 2 + 0], b[0], acc, 0, 0, 0);
      acc = __builtin_amdgcn_mfma_f32_16x16x32_bf16(
          wan2r[m0 * 2 + 1], b[1], acc, 0, 0, 0);
      float e0v = elive ? __expf(fmaxf(acc[0], 0.f)) : 0.f;
      float e1v = elive ? __expf(fmaxf(acc[1], 0.f)) : 0.f;
      float e2v = elive ? __expf(fmaxf(acc[2], 0.f)) : 0.f;
      float e3v = elive ? __expf(fmaxf(acc[3], 0.f)) : 0.f;
      uint2 pk;
      pk.x = cvt_pk_bf16(e0v, e1v);
      pk.y = cvt_pk_bf16(e2v, e3v);
      *(uint2*)&SB[(w16 + nl) * 72 + m0 * 16 + q * 4] = pk;
    }

    // ---- segmented per-dst-run reduction (dst runs via shuffle) ----
    {
      int c = lane;
      int cur = __shfl(my.y, 0);
      float ssum = 0.f, asum = 0.f;
#pragma unroll
      for (int i = 0; i < 16; ++i) {
        int d = __shfl(my.y, i);
        if (d != cur) {
          if (ssum != 0.f) {
            atomicAdd(&sg[(size_t)cur * 64 + c], ssum);
            atomicAdd(&accg[(size_t)cur * 64 + c], asum);
          }
          cur = d; ssum = 0.f; asum = 0.f;
        }
        float ex = bf2f(SB[(w16 + i) * 72 + c]);
        float pay = bf2f(SD[(w16 + i) * 72 + c]);   // pay = delta + v
        ssum += ex;
        asum = fmaf(ex, pay, asum);
      }
      if (ssum != 0.f) {
        atomicAdd(&sg[(size_t)cur * 64 + c], ssum);
        atomicAdd(&accg[(size_t)cur * 64 + c], asum);
      }
    }

    my = nxt;   // rotate prefetched pair
  }
}

// ------------------------- out kernel (transposed MFMA) --------------------

__global__ __launch_bounds__(256) void k_out(const float* __restrict__ accg,
                                             const float* __restrict__ sg,
                                             const unsigned short* __restrict__ wt,
                                             const float* __restrict__ b,
                                             float* __restrict__ out, int N) {
  __shared__ __align__(16) unsigned short WO[64 * 72];
  __shared__ __align__(16) float BO[64];
  int t = threadIdx.x;
  int lane = t & 63, wv = t >> 6;
  int nl = lane & 15, q = lane >> 4;
  int w16 = wv * 16;
  int n0g = blockIdx.x * 64;

  {
    const uint4* s4 = (const uint4*)(wt + 7 * 4608);  // matrix 7 = W_out
    uint4* d4 = (uint4*)WO;
#pragma unroll
    for (int i = 0; i < 3; ++i) {
      int idx = i * 256 + t;
      if (idx < 576) d4[idx] = s4[idx];
    }
  }
  if (t < 64) BO[t] = b[t];

  int row = n0g + w16 + nl;        // my node
  bf16x8 bb[2];
#pragma unroll
  for (int s = 0; s < 2; ++s) {
    union { unsigned int u[4]; bf16x8 v; } fb;
    if (row < N) {
      int kb = s * 32 + q * 8;
      float4 na = *(const float4*)(accg + (size_t)row * 64 + kb);
      float4 nb = *(const float4*)(accg + (size_t)row * 64 + kb + 4);
      float4 da = *(const float4*)(sg + (size_t)row * 64 + kb);
      float4 db = *(const float4*)(sg + (size_t)row * 64 + kb + 4);
      fb.u[0] = cvt_pk_bf16(na.x / (da.x + 1e-16f), na.y / (da.y + 1e-16f));
      fb.u[1] = cvt_pk_bf16(na.z / (da.z + 1e-16f), na.w / (da.w + 1e-16f));
      fb.u[2] = cvt_pk_bf16(nb.x / (db.x + 1e-16f), nb.y / (db.y + 1e-16f));
      fb.u[3] = cvt_pk_bf16(nb.z / (db.z + 1e-16f), nb.w / (db.w + 1e-16f));
    } else {
#pragma unroll
      for (int j = 0; j < 4; ++j) fb.u[j] = 0;
    }
    bb[s] = fb.v;
  }
  __syncthreads();

  bool g = row < N;
#pragma unroll
  for (int m0 = 0; m0 < 4; ++m0) {
    f32x4 acc = *(const f32x4*)&BO[m0 * 16 + q * 4];
    acc = __builtin_amdgcn_mfma_f32_16x16x32_bf16(
        ld_bf8(&WO[(m0 * 16 + nl) * 72 + q * 8]), bb[0], acc, 0, 0, 0);
    acc = __builtin_amdgcn_mfma_f32_16x16x32_bf16(
        ld_bf8(&WO[(m0 * 16 + nl) * 72 + 32 + q * 8]), bb[1], acc, 0, 0, 0);
    if (g) {
      float4 o;
      o.x = fmaxf(acc[0], 0.f);
      o.y = fmaxf(acc[1], 0.f);
      o.z = fmaxf(acc[2], 0.f);
      o.w = fmaxf(acc[3], 0.f);
      *(float4*)(out + (size_t)row * 64 + m0 * 16 + q * 4) = o;
    }
  }
}

// ------------------------------- launcher ----------------------------------

extern "C" void kernel_launch(void* const* d_in, const int* in_sizes, int n_in,
                              void* d_out, int out_size, void* d_ws, size_t ws_size,
                              hipStream_t stream) {
  const float* x     = (const float*)d_in[0];
  const float* pos   = (const float*)d_in[1];
  const int*   eidx  = (const int*)d_in[2];
  const float* W_in  = (const float*)d_in[3];
  const float* b_in  = (const float*)d_in[4];
  const float* ln_g  = (const float*)d_in[5];
  const float* ln_b  = (const float*)d_in[6];
  const float* W_lin = (const float*)d_in[7];
  const float* W_src = (const float*)d_in[8];
  const float* W_dst = (const float*)d_in[9];
  const float* pn_W1 = (const float*)d_in[10];
  const float* pn_b1 = (const float*)d_in[11];
  const float* pn_W2 = (const float*)d_in[12];
  const float* pn_b2 = (const float*)d_in[13];
  const float* an_W1 = (const float*)d_in[14];
  const float* an_b1 = (const float*)d_in[15];
  const float* an_W2 = (const float*)d_in[16];
  const float* an_b2 = (const float*)d_in[17];
  const float* W_out = (const float*)d_in[18];
  const float* b_out = (const float*)d_in[19];
  float* out = (float*)d_out;

  int N = in_sizes[0] / 64;
  int E = in_sizes[2] / 2;
  const int* src = eidx;
  const int* dst = eidx + E;

  char* w = (char*)d_ws;
  auto alloc = [&](size_t bytes) -> void* {
    void* p = (void*)w;
    w += (bytes + 255) & ~(size_t)255;
    return p;
  };
  unsigned short* qg = (unsigned short*)alloc((size_t)N * 64 * 2);
  unsigned short* kg = (unsigned short*)alloc((size_t)N * 64 * 2);
  unsigned short* vg = (unsigned short*)alloc((size_t)N * 64 * 2);
  float* sg   = (float*)alloc((size_t)N * 64 * 4);
  float* accg = (float*)alloc((size_t)N * 64 * 4);   // contiguous after sg
  int2* spair = (int2*)alloc((size_t)E * 8);
  unsigned short* wt = (unsigned short*)alloc(8 * 4608 * 2);
  int* hist   = (int*)alloc((size_t)N * 4);
  int* cursor = (int*)alloc((size_t)N * 4);
  int* bsum   = (int*)alloc(1024 * 4);
  int* incl   = (int*)spair;  // scan scratch aliased into spair (dead before
                              // k_scatter_zero writes spair; scan3 reads 1st)

  int nb1 = (N + 1023) / 1024;               // <= 256 required by k_scan3
  int nodeBlocks = (N + 63) / 64;
  int histBlocks = (E + 255) / 256;
  int zcount = N * 32;                        // sg+accg in float4s
  int zBlocks = (zcount + 255) / 256;
  int numTiles = (E + 63) / 64;
  int edgeGrid = numTiles < 1024 ? numTiles : 1024;  // 4 blocks/CU x 256 CU

  hipMemsetAsync(hist, 0, (size_t)N * 4, stream);
  k_prep<<<8, 256, 0, stream>>>(
      W_in, W_dst, W_src, W_lin, pn_W2, an_W1, an_W2, W_out, wt);
  k_node_hist<<<nodeBlocks + histBlocks, 256, 0, stream>>>(
      x, wt, b_in, ln_g, ln_b, qg, kg, vg, N, dst, hist, E, nodeBlocks);
  k_scan1<<<nb1, 256, 0, stream>>>(hist, incl, bsum, N);
  k_scan3<<<nb1, 256, 0, stream>>>(incl, hist, bsum, cursor, N);
  k_scatter_zero<<<histBlocks + zBlocks, 256, 0, stream>>>(
      src, dst, cursor, spair, E, (float4*)sg, zcount, histBlocks);
  k_edge<<<edgeGrid, 256, 0, stream>>>(spair, pos, qg, kg, vg, wt,
                                       pn_W1, pn_b1, pn_b2, an_b1, an_b2,
                                       sg, accg, E, numTiles);
  k_out<<<nodeBlocks, 256, 0, stream>>>(accg, sg, wt, b_out, out, N);
}

// Round 12
// 450.788 us; speedup vs baseline: 1.1544x; 1.1223x over previous
//
#include <hip/hip_runtime.h>

// ---------------------------------------------------------------------------
// PointTransformerBlock, MI355X.  R24 = R23 with the counting sort reduced
// from TWO atomic passes to ONE; k_edge body UNTOUCHED:
//  R22/R23 measured: each 1.6M-random-atomic pass ~134us @12G atomics/s and
//  does NOT hide under co-dispatched compute (R23: fusion neutral).  So:
//  - Pass A (only atomic pass, fused into k_node's dispatch): slot =
//    atomicAdd(&cnt[d],1); padded[d*64+slot]=(src,dst).  Builds hist AND
//    places the edge -> old scatter pass subsumed.  CAP=64 (Poisson(16)
//    degrees: P(>=64) ~ 1e-19; guarded).
//  - padded (N*64*8B = 51.2MB) ALIASES sg+accg exactly; dead after compact,
//    which is exactly when sg/accg must become zero.
//  - k_compact (atomic-free, coalesced): thread flat=d*64+slot copies its
//    own bucket entry (slot<cnt[d]) to dense spair[base[d]+slot], then
//    zeroes its own 8B -> compaction + sg/accg zero-fill in one ~77MB
//    streaming pass (~20us).  scan1/scan3 unchanged (cursor = excl base).
//  - k_edge reads the identical dense dst-grouped spair (within-dst order
//    differs; reduction only needs grouping).  R21 body verbatim.
//  MFMA layouts (HW-verified, guide §3): A[m=lane&15][k=q*8+j],
//  B[k=q*8+j][n=lane&15], C/D col=lane&15 row=q*4+r.
// ---------------------------------------------------------------------------

typedef __bf16 bf16x8 __attribute__((ext_vector_type(8)));
typedef float f32x4 __attribute__((ext_vector_type(4)));

__device__ inline unsigned short f2bf(float f) {
  return __builtin_bit_cast(unsigned short, (__bf16)f);   // v_cvt (RNE)
}
__device__ inline float bf2f(unsigned short s) {
  return __uint_as_float(((unsigned int)s) << 16);
}
__device__ inline bf16x8 ld_bf8(const unsigned short* p) {
  union { uint4 i; bf16x8 v; } u;
  u.i = *(const uint4*)p;
  return u.v;
}
// packed f32->2xbf16 (gfx950; no builtin -- guide T12/m240). dst.lo=cvt(lo).
__device__ inline unsigned int cvt_pk_bf16(float lo, float hi) {
  unsigned int r;
  asm("v_cvt_pk_bf16_f32 %0, %1, %2" : "=v"(r) : "v"(lo), "v"(hi));
  return r;
}

// --------------------- prep kernel (weights only, 8 blocks) ----------------

__global__ __launch_bounds__(256) void k_prep(
    const float* __restrict__ W_in, const float* __restrict__ W_dst,
    const float* __restrict__ W_src, const float* __restrict__ W_lin,
    const float* __restrict__ pn_W2, const float* __restrict__ an_W1,
    const float* __restrict__ an_W2, const float* __restrict__ W_out,
    unsigned short* __restrict__ wt) {
  int t = threadIdx.x;
  const float* Ws[8] = {W_in, W_dst, W_src, W_lin, pn_W2, an_W1, an_W2, W_out};
  const float* W = Ws[blockIdx.x];
  unsigned short* o = wt + (size_t)blockIdx.x * 4608;
#pragma unroll
  for (int i = 0; i < 16; ++i) {
    int e = i * 256 + t;           // e = k*64 + n  (coalesced read)
    int k = e >> 6, n = e & 63;
    o[n * 72 + k] = f2bf(W[e]);    // wt[n][k] = W^T[n][k]
  }
}

// ------------------------------ sort kernels -------------------------------

// scan1: per-1024-chunk inclusive scan of hist -> incl, chunk sums -> bsum.
__global__ __launch_bounds__(256) void k_scan1(
    const int* __restrict__ hist, int* __restrict__ incl,
    int* __restrict__ bsum, int N) {
  __shared__ int sd[256];
  int t = threadIdx.x;
  int base = blockIdx.x * 1024 + t * 4;
  int v[4]; int ts = 0;
#pragma unroll
  for (int i = 0; i < 4; ++i) {
    int idx = base + i;
    v[i] = (idx < N) ? hist[idx] : 0;
    ts += v[i];
  }
  sd[t] = ts;
  __syncthreads();
  for (int off = 1; off < 256; off <<= 1) {
    int xv = (t >= off) ? sd[t - off] : 0;
    __syncthreads();
    sd[t] += xv;
    __syncthreads();
  }
  int run = sd[t] - ts;
#pragma unroll
  for (int i = 0; i < 4; ++i) {
    run += v[i];
    int idx = base + i;
    if (idx < N) incl[idx] = run;
  }
  if (t == 255) bsum[blockIdx.x] = sd[255];
}

// scan3 with inline block-offset: reduce bsum[0..blockIdx) in-block.
// Requires gridDim <= 256 (N <= 262144).  cursor[id] = exclusive base.
__global__ __launch_bounds__(256) void k_scan3(
    const int* __restrict__ incl, const int* __restrict__ hist,
    const int* __restrict__ bsum, int* __restrict__ cursor, int N) {
  __shared__ int red[256];
  int t = threadIdx.x;
  red[t] = (t < (int)blockIdx.x) ? bsum[t] : 0;
  __syncthreads();
#pragma unroll
  for (int off = 128; off; off >>= 1) {
    if (t < off) red[t] += red[t + off];
    __syncthreads();
  }
  int bo = red[0];
  int base = blockIdx.x * 1024 + t * 4;
#pragma unroll
  for (int i = 0; i < 4; ++i) {
    int id = base + i;
    if (id < N) cursor[id] = bo + incl[id] - hist[id];
  }
}

// compact: padded buckets -> dense spair; zero own 8B (= sg/accg zero-fill).
// No atomics; coalesced.  Thread flat = d*64 + slot owns one bucket cell.
__global__ __launch_bounds__(256) void k_compact(
    int2* __restrict__ padded, const int* __restrict__ cnt,
    const int* __restrict__ base, int2* __restrict__ spair, int N) {
  int flat = blockIdx.x * 256 + threadIdx.x;
  if (flat >= N * 64) return;
  int d = flat >> 6, slot = flat & 63;
  int c = cnt[d];
  if (slot < c) {
    int2 v = padded[flat];
    spair[base[d] + slot] = v;
  }
  padded[flat] = make_int2(0, 0);   // zeroes the aliased sg/accg region
}

// -------- node kernel (transposed MFMA) with FUSED pass-A scatter ----------

__global__ __launch_bounds__(256) void k_node_scat(
    const float* __restrict__ x, const unsigned short* __restrict__ wt,
    const float* __restrict__ b_in, const float* __restrict__ ln_g,
    const float* __restrict__ ln_b,
    unsigned short* __restrict__ qg, unsigned short* __restrict__ kg,
    unsigned short* __restrict__ vg,
    int N, const int* __restrict__ src, const int* __restrict__ dst,
    int* __restrict__ cnt, int2* __restrict__ padded, int E,
    int nodeBlocks) {
  int t = threadIdx.x;

  // ---- fused pass-A blocks: the ONLY atomic pass of the sort ----
  if ((int)blockIdx.x >= nodeBlocks) {
    int e = ((int)blockIdx.x - nodeBlocks) * 256 + t;
    if (e < E) {
      int d = dst[e], s = src[e];
      int slot = atomicAdd(&cnt[d], 1);
      if (slot < 64) padded[(size_t)d * 64 + slot] = make_int2(s, d);
    }
    return;
  }

  __shared__ __align__(16) unsigned short WALL[4 * 64 * 72];
  __shared__ __align__(16) unsigned short HT[64 * 72];   // h [node][ch]
  __shared__ __align__(16) float LNG[64], LNB[64], BIN[64];

  int lane = t & 63, wv = t >> 6;
  int nl = lane & 15, q = lane >> 4;
  int w16 = wv * 16;
  int n0g = blockIdx.x * 64;

  {
    const uint4* s4 = (const uint4*)wt;
    uint4* d4 = (uint4*)WALL;
#pragma unroll
    for (int i = 0; i < 9; ++i) d4[i * 256 + t] = s4[i * 256 + t];
  }
  if (t < 64) { LNG[t] = ln_g[t]; LNB[t] = ln_b[t]; BIN[t] = b_in[t]; }

  int row = n0g + w16 + nl;        // my node
  bf16x8 b[2];                     // B-frag: x[node=nl][k]
#pragma unroll
  for (int s = 0; s < 2; ++s) {
    union { unsigned int u[4]; bf16x8 v; } fb;
    if (row < N) {
      int kb = s * 32 + q * 8;
      float4 xa = *(const float4*)(x + (size_t)row * 64 + kb);
      float4 xb = *(const float4*)(x + (size_t)row * 64 + kb + 4);
      fb.u[0] = cvt_pk_bf16(xa.x, xa.y);
      fb.u[1] = cvt_pk_bf16(xa.z, xa.w);
      fb.u[2] = cvt_pk_bf16(xb.x, xb.y);
      fb.u[3] = cvt_pk_bf16(xb.z, xb.w);
    } else {
#pragma unroll
      for (int j = 0; j < 4; ++j) fb.u[j] = 0;
    }
    b[s] = fb.v;
  }
  __syncthreads();

  // GEMM1: h = relu(x @ W_in + b_in); lane holds ch m0*16+q*4+r of node nl
  f32x4 h[4];
#pragma unroll
  for (int m0 = 0; m0 < 4; ++m0) {
    f32x4 acc = *(const f32x4*)&BIN[m0 * 16 + q * 4];
    acc = __builtin_amdgcn_mfma_f32_16x16x32_bf16(
        ld_bf8(&WALL[(m0 * 16 + nl) * 72 + q * 8]), b[0], acc, 0, 0, 0);
    acc = __builtin_amdgcn_mfma_f32_16x16x32_bf16(
        ld_bf8(&WALL[(m0 * 16 + nl) * 72 + 32 + q * 8]), b[1], acc, 0, 0, 0);
#pragma unroll
    for (int r = 0; r < 4; ++r) acc[r] = fmaxf(acc[r], 0.f);
    h[m0] = acc;
  }

  // LayerNorm over channels of node nl: local 16 + reduce across q-lanes
  float sv = 0.f, sq = 0.f;
#pragma unroll
  for (int m0 = 0; m0 < 4; ++m0)
#pragma unroll
    for (int r = 0; r < 4; ++r) {
      float v = h[m0][r];
      sv += v; sq += v * v;
    }
  sv += __shfl_xor(sv, 16); sq += __shfl_xor(sq, 16);
  sv += __shfl_xor(sv, 32); sq += __shfl_xor(sq, 32);
  float mu = sv * (1.f / 64.f);
  float var = sq * (1.f / 64.f) - mu * mu;
  float rs = rsqrtf(var + 1e-5f);
#pragma unroll
  for (int m0 = 0; m0 < 4; ++m0) {
    f32x4 g4 = *(const f32x4*)&LNG[m0 * 16 + q * 4];
    f32x4 o4 = *(const f32x4*)&LNB[m0 * 16 + q * 4];
    float v0 = (h[m0][0] - mu) * rs * g4[0] + o4[0];
    float v1 = (h[m0][1] - mu) * rs * g4[1] + o4[1];
    float v2 = (h[m0][2] - mu) * rs * g4[2] + o4[2];
    float v3 = (h[m0][3] - mu) * rs * g4[3] + o4[3];
    uint2 pk;
    pk.x = cvt_pk_bf16(v0, v1);
    pk.y = cvt_pk_bf16(v2, v3);
    *(uint2*)&HT[(w16 + nl) * 72 + m0 * 16 + q * 4] = pk;
  }

  b[0] = ld_bf8(&HT[(w16 + nl) * 72 + q * 8]);
  b[1] = ld_bf8(&HT[(w16 + nl) * 72 + 32 + q * 8]);

  unsigned short* Og[3] = {qg, kg, vg};
  bool g = row < N;
#pragma unroll
  for (int m = 0; m < 3; ++m) {
    const unsigned short* Wm = WALL + (m + 1) * 4608;
#pragma unroll
    for (int m0 = 0; m0 < 4; ++m0) {
      f32x4 acc = {0.f, 0.f, 0.f, 0.f};
      acc = __builtin_amdgcn_mfma_f32_16x16x32_bf16(
          ld_bf8(&Wm[(m0 * 16 + nl) * 72 + q * 8]), b[0], acc, 0, 0, 0);
      acc = __builtin_amdgcn_mfma_f32_16x16x32_bf16(
          ld_bf8(&Wm[(m0 * 16 + nl) * 72 + 32 + q * 8]), b[1], acc, 0, 0, 0);
      if (g) {
        uint2 pk;
        pk.x = cvt_pk_bf16(acc[0], acc[1]);
        pk.y = cvt_pk_bf16(acc[2], acc[3]);
        // v (m==2) stored PERMUTED: pos(c)=q*16+m0*4+r so a k_edge lane
        // reads its 16 v-elems as one contiguous 32B block.  q/k unchanged.
        int off = (m == 2) ? (q * 16 + m0 * 4) : (m0 * 16 + q * 4);
        *(uint2*)(Og[m] + (size_t)row * 64 + off) = pk;
      }
    }
  }
}

// ---- edge kernel (persistent, 4 blocks/CU, R21 body verbatim) -------------

__global__ __launch_bounds__(256, 4) void k_edge(
    const int2* __restrict__ spair, const float* __restrict__ pos,
    const unsigned short* __restrict__ qg, const unsigned short* __restrict__ kg,
    const unsigned short* __restrict__ vg,
    const unsigned short* __restrict__ wt,
    const float* __restrict__ pn_W1, const float* __restrict__ pn_b1,
    const float* __restrict__ pn_b2,
    const float* __restrict__ an_b1, const float* __restrict__ an_b2,
    float* __restrict__ sg, float* __restrict__ accg, int E, int numTiles) {
  __shared__ __align__(16) unsigned short WAB[2 * 64 * 72];  // pn_W2 | an_W1
  __shared__ __align__(16) unsigned short SD[64 * 72];   // delta, then pay
  __shared__ __align__(16) unsigned short SB[64 * 72];   // a1, then ex
  __shared__ float W1[3 * 64];
  __shared__ float B1[64];
  __shared__ __align__(16) float B2[64], AB1[64], AB2[64];

  int t = threadIdx.x;
  int lane = t & 63, wv = t >> 6;
  int nl = lane & 15, q = lane >> 4;
  int w16 = wv * 16;

  // ---- one-time staging: pn_W2 + an_W1 to LDS (uint4 memcpy) ----
  {
    const uint4* s4 = (const uint4*)(wt + 4 * 4608);  // matrices 4,5
    uint4* d4 = (uint4*)WAB;
#pragma unroll
    for (int i = 0; i < 5; ++i) {
      int idx = i * 256 + t;
      if (idx < 1152) d4[idx] = s4[idx];
    }
  }
  if (t < 192) W1[t] = pn_W1[t];
  if (t < 64) {
    B1[t] = pn_b1[t];  B2[t] = pn_b2[t];
    AB1[t] = an_b1[t]; AB2[t] = an_b2[t];
  }
  // ---- an_W2 A-frags -> registers (32 VGPR), straight from wt ----
  bf16x8 wan2r[8];
#pragma unroll
  for (int m0 = 0; m0 < 4; ++m0)
#pragma unroll
    for (int s = 0; s < 2; ++s)
      wan2r[m0 * 2 + s] =
          ld_bf8(wt + 6 * 4608 + (m0 * 16 + nl) * 72 + s * 32 + q * 8);
  const unsigned short* WPN2 = WAB;
  const unsigned short* WAN1 = WAB + 4608;
  __syncthreads();   // the ONLY barrier: weights/biases visible to all waves

  // Lane L of wave wv owns edge e0 + w16 + (L&15): its (src,dst) pair "my"
  // IS the tile's cross-lane state (distributed via __shfl, no LDS, no
  // barriers; SD/SB strips rows w16..w16+15 stay wave-private).
  long er_off = w16 + nl;
  int2 my;
  {
    long er = (long)blockIdx.x * 64 + er_off;
    my = (er < E) ? spair[er] : make_int2(0, 0);
  }

  for (int tile = blockIdx.x; tile < numTiles; tile += gridDim.x) {
    long e0 = (long)tile * 64;

    // ---- tile-top fan-out: all gathers issue off prefetched "my" ----
    const unsigned short* qr = qg + (size_t)my.y * 64;
    const unsigned short* kr = kg + (size_t)my.x * 64;
    bf16x8 qf[2], kf[2];
#pragma unroll
    for (int s = 0; s < 2; ++s) {
      int kb = s * 32 + q * 8;
      qf[s] = ld_bf8(qr + kb);
      kf[s] = ld_bf8(kr + kb);
    }
    // v for my OWN edge's src: PERMUTED layout -> one contiguous 32B
    const unsigned short* vr = vg + (size_t)my.x * 64;
    bf16x8 vlo = ld_bf8(vr + q * 16);
    bf16x8 vhi = ld_bf8(vr + q * 16 + 8);
    // pos diffs for my own edge (strip row w16+nl == my edge)
    float p0 = pos[my.y * 3 + 0] - pos[my.x * 3 + 0];
    float p1 = pos[my.y * 3 + 1] - pos[my.x * 3 + 1];
    float p2 = pos[my.y * 3 + 2] - pos[my.x * 3 + 2];

    // ---- prefetch next tile's spair into regs (hide under compute) ----
    int2 nxt = make_int2(0, 0);
    {
      long ntile = (long)tile + gridDim.x;
      if (ntile < numTiles) {
        long ner = ntile * 64 + er_off;
        nxt = (ner < E) ? spair[ner] : make_int2(0, 0);
      }
    }

    bool elive = (e0 + er_off) < E;   // my edge's liveness (col = nl)

    bf16x8 b[2];

    // ---- pos-MLP layer1 (K=3) straight into B-frag registers ----
#pragma unroll
    for (int s = 0; s < 2; ++s) {
      union { unsigned int u[4]; bf16x8 v; } fb;
      int kb = s * 32 + q * 8;
#pragma unroll
      for (int jj = 0; jj < 4; ++jj) {
        int c0 = kb + 2 * jj, c1 = c0 + 1;
        float v0 = fmaf(p0, W1[c0],
                   fmaf(p1, W1[64 + c0],
                   fmaf(p2, W1[128 + c0], B1[c0])));
        float v1 = fmaf(p0, W1[c1],
                   fmaf(p1, W1[64 + c1],
                   fmaf(p2, W1[128 + c1], B1[c1])));
        fb.u[jj] = cvt_pk_bf16(fmaxf(v0, 0.f), fmaxf(v1, 0.f));
      }
      b[s] = fb.v;
    }

    // ---- GEMM1: delta^T = pn_W2^T @ A1^T, bias-in-acc, relu -> SD ----
    f32x4 dlt[4];
#pragma unroll
    for (int m0 = 0; m0 < 4; ++m0) {
      f32x4 acc = *(const f32x4*)&B2[m0 * 16 + q * 4];
      acc = __builtin_amdgcn_mfma_f32_16x16x32_bf16(
          ld_bf8(&WPN2[(m0 * 16 + nl) * 72 + q * 8]), b[0], acc, 0, 0, 0);
      acc = __builtin_amdgcn_mfma_f32_16x16x32_bf16(
          ld_bf8(&WPN2[(m0 * 16 + nl) * 72 + 32 + q * 8]), b[1], acc, 0, 0, 0);
#pragma unroll
      for (int r = 0; r < 4; ++r) acc[r] = fmaxf(acc[r], 0.f);
      dlt[m0] = acc;
      uint2 pk;
      pk.x = cvt_pk_bf16(acc[0], acc[1]);
      pk.y = cvt_pk_bf16(acc[2], acc[3]);
      *(uint2*)&SD[(w16 + nl) * 72 + m0 * 16 + q * 4] = pk;
    }

    // ---- build ai = q[dst]-k[src]+delta in B-frag layout (reads SD) ----
#pragma unroll
    for (int s = 0; s < 2; ++s) {
      int kb = s * 32 + q * 8;
      bf16x8 d8 = ld_bf8(&SD[(w16 + nl) * 72 + kb]);
      union { unsigned int u[4]; bf16x8 v; } fb;
#pragma unroll
      for (int jj = 0; jj < 4; ++jj) {
        float v0 = (float)qf[s][2 * jj]     - (float)kf[s][2 * jj]     + (float)d8[2 * jj];
        float v1 = (float)qf[s][2 * jj + 1] - (float)kf[s][2 * jj + 1] + (float)d8[2 * jj + 1];
        fb.u[jj] = cvt_pk_bf16(v0, v1);
      }
      b[s] = fb.v;
    }

    // ---- overwrite SD with pay = delta + v[src]  (same-wave DS order) ----
#pragma unroll
    for (int m0 = 0; m0 < 4; ++m0) {
      float va0, va1, va2, va3;
      if (m0 == 0)      { va0 = (float)vlo[0]; va1 = (float)vlo[1];
                          va2 = (float)vlo[2]; va3 = (float)vlo[3]; }
      else if (m0 == 1) { va0 = (float)vlo[4]; va1 = (float)vlo[5];
                          va2 = (float)vlo[6]; va3 = (float)vlo[7]; }
      else if (m0 == 2) { va0 = (float)vhi[0]; va1 = (float)vhi[1];
                          va2 = (float)vhi[2]; va3 = (float)vhi[3]; }
      else              { va0 = (float)vhi[4]; va1 = (float)vhi[5];
                          va2 = (float)vhi[6]; va3 = (float)vhi[7]; }
      uint2 pk;
      pk.x = cvt_pk_bf16(dlt[m0][0] + va0, dlt[m0][1] + va1);
      pk.y = cvt_pk_bf16(dlt[m0][2] + va2, dlt[m0][3] + va3);
      *(uint2*)&SD[(w16 + nl) * 72 + m0 * 16 + q * 4] = pk;
    }

    // ---- GEMM2: a1^T = an_W1^T @ ai^T, bias-in-acc, relu -> SB ----
#pragma unroll
    for (int m0 = 0; m0 < 4; ++m0) {
      f32x4 acc = *(const f32x4*)&AB1[m0 * 16 + q * 4];
      acc = __builtin_amdgcn_mfma_f32_16x16x32_bf16(
          ld_bf8(&WAN1[(m0 * 16 + nl) * 72 + q * 8]), b[0], acc, 0, 0, 0);
      acc = __builtin_amdgcn_mfma_f32_16x16x32_bf16(
          ld_bf8(&WAN1[(m0 * 16 + nl) * 72 + 32 + q * 8]), b[1], acc, 0, 0, 0);
      uint2 pk;
      pk.x = cvt_pk_bf16(fmaxf(acc[0], 0.f), fmaxf(acc[1], 0.f));
      pk.y = cvt_pk_bf16(fmaxf(acc[2], 0.f), fmaxf(acc[3], 0.f));
      *(uint2*)&SB[(w16 + nl) * 72 + m0 * 16 + q * 4] = pk;
    }

    // ---- GEMM3: alpha^T = an_W2^T(regs) @ a1^T; ex = exp(relu) -> SB ----
    b[0] = ld_bf8(&SB[(w16 + nl) * 72 + q * 8]);
    b[1] = ld_bf8(&SB[(w16 + nl) * 72 + 32 + q * 8]);
#pragma unroll
    for (int m0 = 0; m0 < 4; ++m0) {
      f32x4 acc = *(const f32x4*)&AB2[m0 * 16 + q * 4];
      acc = __builtin_amdgcn_mfma_f32_16x16x32_bf16(
          wan2r[m0 * 2 + 0], b[0], acc, 0, 0, 0);
      acc = __builtin_amdgcn_mfma_f32_16x16x32_bf16(
          wan2r[m0 * 2 + 1], b[1], acc, 0, 0, 0);
      float e0v = elive ? __expf(fmaxf(acc[0], 0.f)) : 0.f;
      float e1v = elive ? __expf(fmaxf(acc[1], 0.f)) : 0.f;
      float e2v = elive ? __expf(fmaxf(acc[2], 0.f)) : 0.f;
      float e3v = elive ? __expf(fmaxf(acc[3], 0.f)) : 0.f;
      uint2 pk;
      pk.x = cvt_pk_bf16(e0v, e1v);
      pk.y = cvt_pk_bf16(e2v, e3v);
      *(uint2*)&SB[(w16 + nl) * 72 + m0 * 16 + q * 4] = pk;
    }

    // ---- segmented per-dst-run reduction (dst runs via shuffle) ----
    {
      int c = lane;
      int cur = __shfl(my.y, 0);
      float ssum = 0.f, asum = 0.f;
#pragma unroll
      for (int i = 0; i < 16; ++i) {
        int d = __shfl(my.y, i);
        if (d != cur) {
          if (ssum != 0.f) {
            atomicAdd(&sg[(size_t)cur * 64 + c], ssum);
            atomicAdd(&accg[(size_t)cur * 64 + c], asum);
          }
          cur = d; ssum = 0.f; asum = 0.f;
        }
        float ex = bf2f(SB[(w16 + i) * 72 + c]);
        float pay = bf2f(SD[(w16 + i) * 72 + c]);   // pay = delta + v
        ssum += ex;
        asum = fmaf(ex, pay, asum);
      }
      if (ssum != 0.f) {
        atomicAdd(&sg[(size_t)cur * 64 + c], ssum);
        atomicAdd(&accg[(size_t)cur * 64 + c], asum);
      }
    }

    my = nxt;   // rotate prefetched pair
  }
}

// ------------------------- out kernel (transposed MFMA) --------------------

__global__ __launch_bounds__(256) void k_out(const float* __restrict__ accg,
                                             const float* __restrict__ sg,
                                             const unsigned short* __restrict__ wt,
                                             const float* __restrict__ b,
                                             float* __restrict__ out, int N) {
  __shared__ __align__(16) unsigned short WO[64 * 72];
  __shared__ __align__(16) float BO[64];
  int t = threadIdx.x;
  int lane = t & 63, wv = t >> 6;
  int nl = lane & 15, q = lane >> 4;
  int w16 = wv * 16;
  int n0g = blockIdx.x * 64;

  {
    const uint4* s4 = (const uint4*)(wt + 7 * 4608);  // matrix 7 = W_out
    uint4* d4 = (uint4*)WO;
#pragma unroll
    for (int i = 0; i < 3; ++i) {
      int idx = i * 256 + t;
      if (idx < 576) d4[idx] = s4[idx];
    }
  }
  if (t < 64) BO[t] = b[t];

  int row = n0g + w16 + nl;        // my node
  bf16x8 bb[2];
#pragma unroll
  for (int s = 0; s < 2; ++s) {
    union { unsigned int u[4]; bf16x8 v; } fb;
    if (row < N) {
      int kb = s * 32 + q * 8;
      float4 na = *(const float4*)(accg + (size_t)row * 64 + kb);
      float4 nb = *(const float4*)(accg + (size_t)row * 64 + kb + 4);
      float4 da = *(const float4*)(sg + (size_t)row * 64 + kb);
      float4 db = *(const float4*)(sg + (size_t)row * 64 + kb + 4);
      fb.u[0] = cvt_pk_bf16(na.x / (da.x + 1e-16f), na.y / (da.y + 1e-16f));
      fb.u[1] = cvt_pk_bf16(na.z / (da.z + 1e-16f), na.w / (da.w + 1e-16f));
      fb.u[2] = cvt_pk_bf16(nb.x / (db.x + 1e-16f), nb.y / (db.y + 1e-16f));
      fb.u[3] = cvt_pk_bf16(nb.z / (db.z + 1e-16f), nb.w / (db.w + 1e-16f));
    } else {
#pragma unroll
      for (int j = 0; j < 4; ++j) fb.u[j] = 0;
    }
    bb[s] = fb.v;
  }
  __syncthreads();

  bool g = row < N;
#pragma unroll
  for (int m0 = 0; m0 < 4; ++m0) {
    f32x4 acc = *(const f32x4*)&BO[m0 * 16 + q * 4];
    acc = __builtin_amdgcn_mfma_f32_16x16x32_bf16(
        ld_bf8(&WO[(m0 * 16 + nl) * 72 + q * 8]), bb[0], acc, 0, 0, 0);
    acc = __builtin_amdgcn_mfma_f32_16x16x32_bf16(
        ld_bf8(&WO[(m0 * 16 + nl) * 72 + 32 + q * 8]), bb[1], acc, 0, 0, 0);
    if (g) {
      float4 o;
      o.x = fmaxf(acc[0], 0.f);
      o.y = fmaxf(acc[1], 0.f);
      o.z = fmaxf(acc[2], 0.f);
      o.w = fmaxf(acc[3], 0.f);
      *(float4*)(out + (size_t)row * 64 + m0 * 16 + q * 4) = o;
    }
  }
}

// ------------------------------- launcher ----------------------------------

extern "C" void kernel_launch(void* const* d_in, const int* in_sizes, int n_in,
                              void* d_out, int out_size, void* d_ws, size_t ws_size,
                              hipStream_t stream) {
  const float* x     = (const float*)d_in[0];
  const float* pos   = (const float*)d_in[1];
  const int*   eidx  = (const int*)d_in[2];
  const float* W_in  = (const float*)d_in[3];
  const float* b_in  = (const float*)d_in[4];
  const float* ln_g  = (const float*)d_in[5];
  const float* ln_b  = (const float*)d_in[6];
  const float* W_lin = (const float*)d_in[7];
  const float* W_src = (const float*)d_in[8];
  const float* W_dst = (const float*)d_in[9];
  const float* pn_W1 = (const float*)d_in[10];
  const float* pn_b1 = (const float*)d_in[11];
  const float* pn_W2 = (const float*)d_in[12];
  const float* pn_b2 = (const float*)d_in[13];
  const float* an_W1 = (const float*)d_in[14];
  const float* an_b1 = (const float*)d_in[15];
  const float* an_W2 = (const float*)d_in[16];
  const float* an_b2 = (const float*)d_in[17];
  const float* W_out = (const float*)d_in[18];
  const float* b_out = (const float*)d_in[19];
  float* out = (float*)d_out;

  int N = in_sizes[0] / 64;
  int E = in_sizes[2] / 2;
  const int* src = eidx;
  const int* dst = eidx + E;

  char* w = (char*)d_ws;
  auto alloc = [&](size_t bytes) -> void* {
    void* p = (void*)w;
    w += (bytes + 255) & ~(size_t)255;
    return p;
  };
  unsigned short* qg = (unsigned short*)alloc((size_t)N * 64 * 2);
  unsigned short* kg = (unsigned short*)alloc((size_t)N * 64 * 2);
  unsigned short* vg = (unsigned short*)alloc((size_t)N * 64 * 2);
  float* sg   = (float*)alloc((size_t)N * 64 * 4);
  float* accg = (float*)alloc((size_t)N * 64 * 4);   // contiguous after sg
  int2* spair = (int2*)alloc((size_t)E * 8);
  unsigned short* wt = (unsigned short*)alloc(8 * 4608 * 2);
  int* hist   = (int*)alloc((size_t)N * 4);          // = cnt (pass A)
  int* cursor = (int*)alloc((size_t)N * 4);          // = exclusive base
  int* bsum   = (int*)alloc(1024 * 4);
  int* incl   = (int*)spair;  // scan scratch aliased into spair (dead before
                              // k_compact writes spair; scan3 reads first)
  int2* padded = (int2*)sg;   // N*64*8B buckets alias sg+accg exactly;
                              // k_compact zeroes them after compaction

  int nb1 = (N + 1023) / 1024;               // <= 256 required by k_scan3
  int nodeBlocks = (N + 63) / 64;
  int scatBlocks = (E + 255) / 256;
  int compactBlocks = (N * 64 + 255) / 256;
  int numTiles = (E + 63) / 64;
  int edgeGrid = numTiles < 1024 ? numTiles : 1024;  // 4 blocks/CU x 256 CU

  hipMemsetAsync(hist, 0, (size_t)N * 4, stream);
  k_prep<<<8, 256, 0, stream>>>(
      W_in, W_dst, W_src, W_lin, pn_W2, an_W1, an_W2, W_out, wt);
  k_node_scat<<<nodeBlocks + scatBlocks, 256, 0, stream>>>(
      x, wt, b_in, ln_g, ln_b, qg, kg, vg, N, src, dst, hist, padded, E,
      nodeBlocks);
  k_scan1<<<nb1, 256, 0, stream>>>(hist, incl, bsum, N);
  k_scan3<<<nb1, 256, 0, stream>>>(incl, hist, bsum, cursor, N);
  k_compact<<<compactBlocks, 256, 0, stream>>>(padded, hist, cursor, spair, N);
  k_edge<<<edgeGrid, 256, 0, stream>>>(spair, pos, qg, kg, vg, wt,
                                       pn_W1, pn_b1, pn_b2, an_b1, an_b2,
                                       sg, accg, E, numTiles);
  k_out<<<nodeBlocks, 256, 0, stream>>>(accg, sg, wt, b_out, out, N);
}

// Round 13
// 386.883 us; speedup vs baseline: 1.3451x; 1.1652x over previous
//
#include <hip/hip_runtime.h>

// ---------------------------------------------------------------------------
// PointTransformerBlock, MI355X.  R25 = R24 with the 1.6M-random-atomic sort
// pass replaced by a two-level LDS-binned radix sort; k_edge body UNTOUCHED:
//  R24 ledger: pass A ~220us (atomic-rate floor 12G/s + 64B-line RMW
//  amplification of 1.6M random 8B bucket writes).  Fix = LDS binning:
//  - k_s1: 98 blocks x 16384 edges; LDS hist over CB=782 coarse buckets
//    (k=dst>>7); ONE global atomicAdd per (block,bucket) (~77K atomics,
//    20x fewer); edges written to padded coarse buckets (CAP=2560 =
//    mean 2048 + 11 sigma) in per-block contiguous segments.
//  - k_s1scan: 1-block exclusive scan of coarse counts -> cbase.
//  - k_s2: one block per coarse bucket (~2048 edges, 128 dst): LDS hist +
//    LDS scan + scatter to final spair positions (writes inside a
//    contiguous ~16KB region -> L2-resident).
//  - pcoarse (16MB) aliases sg; sg+accg zeroed by ONE memset after S2.
//  - k_node back to plain (no fused scat); k_prep/k_edge/k_out = R24.
//  MFMA layouts (HW-verified, guide §3): A[m=lane&15][k=q*8+j],
//  B[k=q*8+j][n=lane&15], C/D col=lane&15 row=q*4+r.
// ---------------------------------------------------------------------------

typedef __bf16 bf16x8 __attribute__((ext_vector_type(8)));
typedef float f32x4 __attribute__((ext_vector_type(4)));

#define SRT_SH   7          // coarse bucket = 128 dst values
#define SRT_CAP  2560       // padded coarse bucket capacity (mean 2048)
#define SRT_EPB  16384      // edges per k_s1 block

__device__ inline unsigned short f2bf(float f) {
  return __builtin_bit_cast(unsigned short, (__bf16)f);   // v_cvt (RNE)
}
__device__ inline float bf2f(unsigned short s) {
  return __uint_as_float(((unsigned int)s) << 16);
}
__device__ inline bf16x8 ld_bf8(const unsigned short* p) {
  union { uint4 i; bf16x8 v; } u;
  u.i = *(const uint4*)p;
  return u.v;
}
// packed f32->2xbf16 (gfx950; no builtin -- guide T12/m240). dst.lo=cvt(lo).
__device__ inline unsigned int cvt_pk_bf16(float lo, float hi) {
  unsigned int r;
  asm("v_cvt_pk_bf16_f32 %0, %1, %2" : "=v"(r) : "v"(lo), "v"(hi));
  return r;
}

// --------------------- prep kernel (weights only, 8 blocks) ----------------

__global__ __launch_bounds__(256) void k_prep(
    const float* __restrict__ W_in, const float* __restrict__ W_dst,
    const float* __restrict__ W_src, const float* __restrict__ W_lin,
    const float* __restrict__ pn_W2, const float* __restrict__ an_W1,
    const float* __restrict__ an_W2, const float* __restrict__ W_out,
    unsigned short* __restrict__ wt) {
  int t = threadIdx.x;
  const float* Ws[8] = {W_in, W_dst, W_src, W_lin, pn_W2, an_W1, an_W2, W_out};
  const float* W = Ws[blockIdx.x];
  unsigned short* o = wt + (size_t)blockIdx.x * 4608;
#pragma unroll
  for (int i = 0; i < 16; ++i) {
    int e = i * 256 + t;           // e = k*64 + n  (coalesced read)
    int k = e >> 6, n = e & 63;
    o[n * 72 + k] = f2bf(W[e]);    // wt[n][k] = W^T[n][k]
  }
}

// --------------------- radix sort: coarse classify -------------------------

__global__ __launch_bounds__(256) void k_s1(
    const int* __restrict__ src, const int* __restrict__ dst, int E, int CB,
    int* __restrict__ ccnt, int2* __restrict__ pcoarse) {
  __shared__ int hist[1024];
  __shared__ int offs[1024];
  __shared__ int cur[1024];
  int t = threadIdx.x;
  for (int i = t; i < 1024; i += 256) { hist[i] = 0; cur[i] = 0; }
  __syncthreads();
  long e0 = (long)blockIdx.x * SRT_EPB;
  int nE = (int)(((long)E - e0) < SRT_EPB ? ((long)E - e0) : SRT_EPB);
  // phase a: LDS histogram over coarse buckets
  for (int i = t; i < nE; i += 256)
    atomicAdd(&hist[dst[e0 + i] >> SRT_SH], 1);
  __syncthreads();
  // phase b: one global reservation per (block, bucket)
  for (int k = t; k < CB; k += 256) {
    int h = hist[k];
    offs[k] = (h > 0) ? atomicAdd(&ccnt[k], h) : 0;
  }
  __syncthreads();
  // phase c: write edges into padded coarse buckets (contiguous segments)
  for (int i = t; i < nE; i += 256) {
    int s = src[e0 + i], d = dst[e0 + i];
    int k = d >> SRT_SH;
    int p = offs[k] + atomicAdd(&cur[k], 1);
    if (p < SRT_CAP) pcoarse[(size_t)k * SRT_CAP + p] = make_int2(s, d);
  }
}

// one-block exclusive scan of coarse counts (CB <= 1024)
__global__ __launch_bounds__(256) void k_s1scan(
    const int* __restrict__ ccnt, int* __restrict__ cbase, int CB) {
  __shared__ int sd[256];
  int t = threadIdx.x;
  int v[4]; int ts = 0;
#pragma unroll
  for (int i = 0; i < 4; ++i) {
    int idx = t * 4 + i;
    int c = (idx < CB) ? min(ccnt[idx], SRT_CAP) : 0;
    v[i] = c; ts += c;
  }
  sd[t] = ts;
  __syncthreads();
  for (int off = 1; off < 256; off <<= 1) {
    int xv = (t >= off) ? sd[t - off] : 0;
    __syncthreads();
    sd[t] += xv;
    __syncthreads();
  }
  int run = sd[t] - ts;
#pragma unroll
  for (int i = 0; i < 4; ++i) {
    int idx = t * 4 + i;
    if (idx < CB) cbase[idx] = run;
    run += v[i];
  }
}

// --------------------- radix sort: per-bucket refine -----------------------

__global__ __launch_bounds__(256) void k_s2(
    const int2* __restrict__ pcoarse, const int* __restrict__ ccnt,
    const int* __restrict__ cbase, int2* __restrict__ spair) {
  __shared__ int dh[128], dcur[128], dbase[128], sd[128];
  int t = threadIdx.x;
  int k = blockIdx.x;
  if (t < 128) { dh[t] = 0; dcur[t] = 0; }
  __syncthreads();
  int cnt = min(ccnt[k], SRT_CAP);
  const int2* bb = pcoarse + (size_t)k * SRT_CAP;
  int dlo = k << SRT_SH;
  for (int i = t; i < cnt; i += 256)
    atomicAdd(&dh[bb[i].y - dlo], 1);
  __syncthreads();
  // exclusive scan of dh[128]
  if (t < 128) sd[t] = dh[t];
  __syncthreads();
  for (int off = 1; off < 128; off <<= 1) {
    int xv = 0;
    if (t < 128 && t >= off) xv = sd[t - off];
    __syncthreads();
    if (t < 128) sd[t] += xv;
    __syncthreads();
  }
  if (t < 128) dbase[t] = cbase[k] + sd[t] - dh[t];
  __syncthreads();
  for (int i = t; i < cnt; i += 256) {
    int2 e = bb[i];
    int j = e.y - dlo;
    int p = dbase[j] + atomicAdd(&dcur[j], 1);
    spair[p] = e;
  }
}

// ---------------- node kernel (transposed MFMA, plain) ---------------------

__global__ __launch_bounds__(256) void k_node(
    const float* __restrict__ x, const unsigned short* __restrict__ wt,
    const float* __restrict__ b_in, const float* __restrict__ ln_g,
    const float* __restrict__ ln_b,
    unsigned short* __restrict__ qg, unsigned short* __restrict__ kg,
    unsigned short* __restrict__ vg, int N) {
  int t = threadIdx.x;

  __shared__ __align__(16) unsigned short WALL[4 * 64 * 72];
  __shared__ __align__(16) unsigned short HT[64 * 72];   // h [node][ch]
  __shared__ __align__(16) float LNG[64], LNB[64], BIN[64];

  int lane = t & 63, wv = t >> 6;
  int nl = lane & 15, q = lane >> 4;
  int w16 = wv * 16;
  int n0g = blockIdx.x * 64;

  {
    const uint4* s4 = (const uint4*)wt;
    uint4* d4 = (uint4*)WALL;
#pragma unroll
    for (int i = 0; i < 9; ++i) d4[i * 256 + t] = s4[i * 256 + t];
  }
  if (t < 64) { LNG[t] = ln_g[t]; LNB[t] = ln_b[t]; BIN[t] = b_in[t]; }

  int row = n0g + w16 + nl;        // my node
  bf16x8 b[2];                     // B-frag: x[node=nl][k]
#pragma unroll
  for (int s = 0; s < 2; ++s) {
    union { unsigned int u[4]; bf16x8 v; } fb;
    if (row < N) {
      int kb = s * 32 + q * 8;
      float4 xa = *(const float4*)(x + (size_t)row * 64 + kb);
      float4 xb = *(const float4*)(x + (size_t)row * 64 + kb + 4);
      fb.u[0] = cvt_pk_bf16(xa.x, xa.y);
      fb.u[1] = cvt_pk_bf16(xa.z, xa.w);
      fb.u[2] = cvt_pk_bf16(xb.x, xb.y);
      fb.u[3] = cvt_pk_bf16(xb.z, xb.w);
    } else {
#pragma unroll
      for (int j = 0; j < 4; ++j) fb.u[j] = 0;
    }
    b[s] = fb.v;
  }
  __syncthreads();

  // GEMM1: h = relu(x @ W_in + b_in); lane holds ch m0*16+q*4+r of node nl
  f32x4 h[4];
#pragma unroll
  for (int m0 = 0; m0 < 4; ++m0) {
    f32x4 acc = *(const f32x4*)&BIN[m0 * 16 + q * 4];
    acc = __builtin_amdgcn_mfma_f32_16x16x32_bf16(
        ld_bf8(&WALL[(m0 * 16 + nl) * 72 + q * 8]), b[0], acc, 0, 0, 0);
    acc = __builtin_amdgcn_mfma_f32_16x16x32_bf16(
        ld_bf8(&WALL[(m0 * 16 + nl) * 72 + 32 + q * 8]), b[1], acc, 0, 0, 0);
#pragma unroll
    for (int r = 0; r < 4; ++r) acc[r] = fmaxf(acc[r], 0.f);
    h[m0] = acc;
  }

  // LayerNorm over channels of node nl: local 16 + reduce across q-lanes
  float sv = 0.f, sq = 0.f;
#pragma unroll
  for (int m0 = 0; m0 < 4; ++m0)
#pragma unroll
    for (int r = 0; r < 4; ++r) {
      float v = h[m0][r];
      sv += v; sq += v * v;
    }
  sv += __shfl_xor(sv, 16); sq += __shfl_xor(sq, 16);
  sv += __shfl_xor(sv, 32); sq += __shfl_xor(sq, 32);
  float mu = sv * (1.f / 64.f);
  float var = sq * (1.f / 64.f) - mu * mu;
  float rs = rsqrtf(var + 1e-5f);
#pragma unroll
  for (int m0 = 0; m0 < 4; ++m0) {
    f32x4 g4 = *(const f32x4*)&LNG[m0 * 16 + q * 4];
    f32x4 o4 = *(const f32x4*)&LNB[m0 * 16 + q * 4];
    float v0 = (h[m0][0] - mu) * rs * g4[0] + o4[0];
    float v1 = (h[m0][1] - mu) * rs * g4[1] + o4[1];
    float v2 = (h[m0][2] - mu) * rs * g4[2] + o4[2];
    float v3 = (h[m0][3] - mu) * rs * g4[3] + o4[3];
    uint2 pk;
    pk.x = cvt_pk_bf16(v0, v1);
    pk.y = cvt_pk_bf16(v2, v3);
    *(uint2*)&HT[(w16 + nl) * 72 + m0 * 16 + q * 4] = pk;
  }

  b[0] = ld_bf8(&HT[(w16 + nl) * 72 + q * 8]);
  b[1] = ld_bf8(&HT[(w16 + nl) * 72 + 32 + q * 8]);

  unsigned short* Og[3] = {qg, kg, vg};
  bool g = row < N;
#pragma unroll
  for (int m = 0; m < 3; ++m) {
    const unsigned short* Wm = WALL + (m + 1) * 4608;
#pragma unroll
    for (int m0 = 0; m0 < 4; ++m0) {
      f32x4 acc = {0.f, 0.f, 0.f, 0.f};
      acc = __builtin_amdgcn_mfma_f32_16x16x32_bf16(
          ld_bf8(&Wm[(m0 * 16 + nl) * 72 + q * 8]), b[0], acc, 0, 0, 0);
      acc = __builtin_amdgcn_mfma_f32_16x16x32_bf16(
          ld_bf8(&Wm[(m0 * 16 + nl) * 72 + 32 + q * 8]), b[1], acc, 0, 0, 0);
      if (g) {
        uint2 pk;
        pk.x = cvt_pk_bf16(acc[0], acc[1]);
        pk.y = cvt_pk_bf16(acc[2], acc[3]);
        // v (m==2) stored PERMUTED: pos(c)=q*16+m0*4+r so a k_edge lane
        // reads its 16 v-elems as one contiguous 32B block.  q/k unchanged.
        int off = (m == 2) ? (q * 16 + m0 * 4) : (m0 * 16 + q * 4);
        *(uint2*)(Og[m] + (size_t)row * 64 + off) = pk;
      }
    }
  }
}

// ---- edge kernel (persistent, 4 blocks/CU, R21/R24 body verbatim) ---------

__global__ __launch_bounds__(256, 4) void k_edge(
    const int2* __restrict__ spair, const float* __restrict__ pos,
    const unsigned short* __restrict__ qg, const unsigned short* __restrict__ kg,
    const unsigned short* __restrict__ vg,
    const unsigned short* __restrict__ wt,
    const float* __restrict__ pn_W1, const float* __restrict__ pn_b1,
    const float* __restrict__ pn_b2,
    const float* __restrict__ an_b1, const float* __restrict__ an_b2,
    float* __restrict__ sg, float* __restrict__ accg, int E, int numTiles) {
  __shared__ __align__(16) unsigned short WAB[2 * 64 * 72];  // pn_W2 | an_W1
  __shared__ __align__(16) unsigned short SD[64 * 72];   // delta, then pay
  __shared__ __align__(16) unsigned short SB[64 * 72];   // a1, then ex
  __shared__ float W1[3 * 64];
  __shared__ float B1[64];
  __shared__ __align__(16) float B2[64], AB1[64], AB2[64];

  int t = threadIdx.x;
  int lane = t & 63, wv = t >> 6;
  int nl = lane & 15, q = lane >> 4;
  int w16 = wv * 16;

  // ---- one-time staging: pn_W2 + an_W1 to LDS (uint4 memcpy) ----
  {
    const uint4* s4 = (const uint4*)(wt + 4 * 4608);  // matrices 4,5
    uint4* d4 = (uint4*)WAB;
#pragma unroll
    for (int i = 0; i < 5; ++i) {
      int idx = i * 256 + t;
      if (idx < 1152) d4[idx] = s4[idx];
    }
  }
  if (t < 192) W1[t] = pn_W1[t];
  if (t < 64) {
    B1[t] = pn_b1[t];  B2[t] = pn_b2[t];
    AB1[t] = an_b1[t]; AB2[t] = an_b2[t];
  }
  // ---- an_W2 A-frags -> registers (32 VGPR), straight from wt ----
  bf16x8 wan2r[8];
#pragma unroll
  for (int m0 = 0; m0 < 4; ++m0)
#pragma unroll
    for (int s = 0; s < 2; ++s)
      wan2r[m0 * 2 + s] =
          ld_bf8(wt + 6 * 4608 + (m0 * 16 + nl) * 72 + s * 32 + q * 8);
  const unsigned short* WPN2 = WAB;
  const unsigned short* WAN1 = WAB + 4608;
  __syncthreads();   // the ONLY barrier: weights/biases visible to all waves

  // Lane L of wave wv owns edge e0 + w16 + (L&15): its (src,dst) pair "my"
  // IS the tile's cross-lane state (distributed via __shfl, no LDS, no
  // barriers; SD/SB strips rows w16..w16+15 stay wave-private).
  long er_off = w16 + nl;
  int2 my;
  {
    long er = (long)blockIdx.x * 64 + er_off;
    my = (er < E) ? spair[er] : make_int2(0, 0);
  }

  for (int tile = blockIdx.x; tile < numTiles; tile += gridDim.x) {
    long e0 = (long)tile * 64;

    // ---- tile-top fan-out: all gathers issue off prefetched "my" ----
    const unsigned short* qr = qg + (size_t)my.y * 64;
    const unsigned short* kr = kg + (size_t)my.x * 64;
    bf16x8 qf[2], kf[2];
#pragma unroll
    for (int s = 0; s < 2; ++s) {
      int kb = s * 32 + q * 8;
      qf[s] = ld_bf8(qr + kb);
      kf[s] = ld_bf8(kr + kb);
    }
    // v for my OWN edge's src: PERMUTED layout -> one contiguous 32B
    const unsigned short* vr = vg + (size_t)my.x * 64;
    bf16x8 vlo = ld_bf8(vr + q * 16);
    bf16x8 vhi = ld_bf8(vr + q * 16 + 8);
    // pos diffs for my own edge (strip row w16+nl == my edge)
    float p0 = pos[my.y * 3 + 0] - pos[my.x * 3 + 0];
    float p1 = pos[my.y * 3 + 1] - pos[my.x * 3 + 1];
    float p2 = pos[my.y * 3 + 2] - pos[my.x * 3 + 2];

    // ---- prefetch next tile's spair into regs (hide under compute) ----
    int2 nxt = make_int2(0, 0);
    {
      long ntile = (long)tile + gridDim.x;
      if (ntile < numTiles) {
        long ner = ntile * 64 + er_off;
        nxt = (ner < E) ? spair[ner] : make_int2(0, 0);
      }
    }

    bool elive = (e0 + er_off) < E;   // my edge's liveness (col = nl)

    bf16x8 b[2];

    // ---- pos-MLP layer1 (K=3) straight into B-frag registers ----
#pragma unroll
    for (int s = 0; s < 2; ++s) {
      union { unsigned int u[4]; bf16x8 v; } fb;
      int kb = s * 32 + q * 8;
#pragma unroll
      for (int jj = 0; jj < 4; ++jj) {
        int c0 = kb + 2 * jj, c1 = c0 + 1;
        float v0 = fmaf(p0, W1[c0],
                   fmaf(p1, W1[64 + c0],
                   fmaf(p2, W1[128 + c0], B1[c0])));
        float v1 = fmaf(p0, W1[c1],
                   fmaf(p1, W1[64 + c1],
                   fmaf(p2, W1[128 + c1], B1[c1])));
        fb.u[jj] = cvt_pk_bf16(fmaxf(v0, 0.f), fmaxf(v1, 0.f));
      }
      b[s] = fb.v;
    }

    // ---- GEMM1: delta^T = pn_W2^T @ A1^T, bias-in-acc, relu -> SD ----
    f32x4 dlt[4];
#pragma unroll
    for (int m0 = 0; m0 < 4; ++m0) {
      f32x4 acc = *(const f32x4*)&B2[m0 * 16 + q * 4];
      acc = __builtin_amdgcn_mfma_f32_16x16x32_bf16(
          ld_bf8(&WPN2[(m0 * 16 + nl) * 72 + q * 8]), b[0], acc, 0, 0, 0);
      acc = __builtin_amdgcn_mfma_f32_16x16x32_bf16(
          ld_bf8(&WPN2[(m0 * 16 + nl) * 72 + 32 + q * 8]), b[1], acc, 0, 0, 0);
#pragma unroll
      for (int r = 0; r < 4; ++r) acc[r] = fmaxf(acc[r], 0.f);
      dlt[m0] = acc;
      uint2 pk;
      pk.x = cvt_pk_bf16(acc[0], acc[1]);
      pk.y = cvt_pk_bf16(acc[2], acc[3]);
      *(uint2*)&SD[(w16 + nl) * 72 + m0 * 16 + q * 4] = pk;
    }

    // ---- build ai = q[dst]-k[src]+delta in B-frag layout (reads SD) ----
#pragma unroll
    for (int s = 0; s < 2; ++s) {
      int kb = s * 32 + q * 8;
      bf16x8 d8 = ld_bf8(&SD[(w16 + nl) * 72 + kb]);
      union { unsigned int u[4]; bf16x8 v; } fb;
#pragma unroll
      for (int jj = 0; jj < 4; ++jj) {
        float v0 = (float)qf[s][2 * jj]     - (float)kf[s][2 * jj]     + (float)d8[2 * jj];
        float v1 = (float)qf[s][2 * jj + 1] - (float)kf[s][2 * jj + 1] + (float)d8[2 * jj + 1];
        fb.u[jj] = cvt_pk_bf16(v0, v1);
      }
      b[s] = fb.v;
    }

    // ---- overwrite SD with pay = delta + v[src]  (same-wave DS order) ----
#pragma unroll
    for (int m0 = 0; m0 < 4; ++m0) {
      float va0, va1, va2, va3;
      if (m0 == 0)      { va0 = (float)vlo[0]; va1 = (float)vlo[1];
                          va2 = (float)vlo[2]; va3 = (float)vlo[3]; }
      else if (m0 == 1) { va0 = (float)vlo[4]; va1 = (float)vlo[5];
                          va2 = (float)vlo[6]; va3 = (float)vlo[7]; }
      else if (m0 == 2) { va0 = (float)vhi[0]; va1 = (float)vhi[1];
                          va2 = (float)vhi[2]; va3 = (float)vhi[3]; }
      else              { va0 = (float)vhi[4]; va1 = (float)vhi[5];
                          va2 = (float)vhi[6]; va3 = (float)vhi[7]; }
      uint2 pk;
      pk.x = cvt_pk_bf16(dlt[m0][0] + va0, dlt[m0][1] + va1);
      pk.y = cvt_pk_bf16(dlt[m0][2] + va2, dlt[m0][3] + va3);
      *(uint2*)&SD[(w16 + nl) * 72 + m0 * 16 + q * 4] = pk;
    }

    // ---- GEMM2: a1^T = an_W1^T @ ai^T, bias-in-acc, relu -> SB ----
#pragma unroll
    for (int m0 = 0; m0 < 4; ++m0) {
      f32x4 acc = *(const f32x4*)&AB1[m0 * 16 + q * 4];
      acc = __builtin_amdgcn_mfma_f32_16x16x32_bf16(
          ld_bf8(&WAN1[(m0 * 16 + nl) * 72 + q * 8]), b[0], acc, 0, 0, 0);
      acc = __builtin_amdgcn_mfma_f32_16x16x32_bf16(
          ld_bf8(&WAN1[(m0 * 16 + nl) * 72 + 32 + q * 8]), b[1], acc, 0, 0, 0);
      uint2 pk;
      pk.x = cvt_pk_bf16(fmaxf(acc[0], 0.f), fmaxf(acc[1], 0.f));
      pk.y = cvt_pk_bf16(fmaxf(acc[2], 0.f), fmaxf(acc[3], 0.f));
      *(uint2*)&SB[(w16 + nl) * 72 + m0 * 16 + q * 4] = pk;
    }

    // ---- GEMM3: alpha^T = an_W2^T(regs) @ a1^T; ex = exp(relu) -> SB ----
    b[0] = ld_bf8(&SB[(w16 + nl) * 72 + q * 8]);
    b[1] = ld_bf8(&SB[(w16 + nl) * 72 + 32 + q * 8]);
#pragma unroll
    for (int m0 = 0; m0 < 4; ++m0) {
      f32x4 acc = *(const f32x4*)&AB2[m0 * 16 + q * 4];
      acc = __builtin_amdgcn_mfma_f32_16x16x32_bf16(
          wan2r[m0 * 2 + 0], b[0], acc, 0, 0, 0);
      acc = __builtin_amdgcn_mfma_f32_16x16x32_bf16(
          wan2r[m0 * 2 + 1], b[1], acc, 0, 0, 0);
      float e0v = elive ? __expf(fmaxf(acc[0], 0.f)) : 0.f;
      float e1v = elive ? __expf(fmaxf(acc[1], 0.f)) : 0.f;
      float e2v = elive ? __expf(fmaxf(acc[2], 0.f)) : 0.f;
      float e3v = elive ? __expf(fmaxf(acc[3], 0.f)) : 0.f;
      uint2 pk;
      pk.x = cvt_pk_bf16(e0v, e1v);
      pk.y = cvt_pk_bf16(e2v, e3v);
      *(uint2*)&SB[(w16 + nl) * 72 + m0 * 16 + q * 4] = pk;
    }

    // ---- segmented per-dst-run reduction (dst runs via shuffle) ----
    {
      int c = lane;
      int cur = __shfl(my.y, 0);
      float ssum = 0.f, asum = 0.f;
#pragma unroll
      for (int i = 0; i < 16; ++i) {
        int d = __shfl(my.y, i);
        if (d != cur) {
          if (ssum != 0.f) {
            atomicAdd(&sg[(size_t)cur * 64 + c], ssum);
            atomicAdd(&accg[(size_t)cur * 64 + c], asum);
          }
          cur = d; ssum = 0.f; asum = 0.f;
        }
        float ex = bf2f(SB[(w16 + i) * 72 + c]);
        float pay = bf2f(SD[(w16 + i) * 72 + c]);   // pay = delta + v
        ssum += ex;
        asum = fmaf(ex, pay, asum);
      }
      if (ssum != 0.f) {
        atomicAdd(&sg[(size_t)cur * 64 + c], ssum);
        atomicAdd(&accg[(size_t)cur * 64 + c], asum);
      }
    }

    my = nxt;   // rotate prefetched pair
  }
}

// ------------------------- out kernel (transposed MFMA) --------------------

__global__ __launch_bounds__(256) void k_out(const float* __restrict__ accg,
                                             const float* __restrict__ sg,
                                             const unsigned short* __restrict__ wt,
                                             const float* __restrict__ b,
                                             float* __restrict__ out, int N) {
  __shared__ __align__(16) unsigned short WO[64 * 72];
  __shared__ __align__(16) float BO[64];
  int t = threadIdx.x;
  int lane = t & 63, wv = t >> 6;
  int nl = lane & 15, q = lane >> 4;
  int w16 = wv * 16;
  int n0g = blockIdx.x * 64;

  {
    const uint4* s4 = (const uint4*)(wt + 7 * 4608);  // matrix 7 = W_out
    uint4* d4 = (uint4*)WO;
#pragma unroll
    for (int i = 0; i < 3; ++i) {
      int idx = i * 256 + t;
      if (idx < 576) d4[idx] = s4[idx];
    }
  }
  if (t < 64) BO[t] = b[t];

  int row = n0g + w16 + nl;        // my node
  bf16x8 bb[2];
#pragma unroll
  for (int s = 0; s < 2; ++s) {
    union { unsigned int u[4]; bf16x8 v; } fb;
    if (row < N) {
      int kb = s * 32 + q * 8;
      float4 na = *(const float4*)(accg + (size_t)row * 64 + kb);
      float4 nb = *(const float4*)(accg + (size_t)row * 64 + kb + 4);
      float4 da = *(const float4*)(sg + (size_t)row * 64 + kb);
      float4 db = *(const float4*)(sg + (size_t)row * 64 + kb + 4);
      fb.u[0] = cvt_pk_bf16(na.x / (da.x + 1e-16f), na.y / (da.y + 1e-16f));
      fb.u[1] = cvt_pk_bf16(na.z / (da.z + 1e-16f), na.w / (da.w + 1e-16f));
      fb.u[2] = cvt_pk_bf16(nb.x / (db.x + 1e-16f), nb.y / (db.y + 1e-16f));
      fb.u[3] = cvt_pk_bf16(nb.z / (db.z + 1e-16f), nb.w / (db.w + 1e-16f));
    } else {
#pragma unroll
      for (int j = 0; j < 4; ++j) fb.u[j] = 0;
    }
    bb[s] = fb.v;
  }
  __syncthreads();

  bool g = row < N;
#pragma unroll
  for (int m0 = 0; m0 < 4; ++m0) {
    f32x4 acc = *(const f32x4*)&BO[m0 * 16 + q * 4];
    acc = __builtin_amdgcn_mfma_f32_16x16x32_bf16(
        ld_bf8(&WO[(m0 * 16 + nl) * 72 + q * 8]), bb[0], acc, 0, 0, 0);
    acc = __builtin_amdgcn_mfma_f32_16x16x32_bf16(
        ld_bf8(&WO[(m0 * 16 + nl) * 72 + 32 + q * 8]), bb[1], acc, 0, 0, 0);
    if (g) {
      float4 o;
      o.x = fmaxf(acc[0], 0.f);
      o.y = fmaxf(acc[1], 0.f);
      o.z = fmaxf(acc[2], 0.f);
      o.w = fmaxf(acc[3], 0.f);
      *(float4*)(out + (size_t)row * 64 + m0 * 16 + q * 4) = o;
    }
  }
}

// ------------------------------- launcher ----------------------------------

extern "C" void kernel_launch(void* const* d_in, const int* in_sizes, int n_in,
                              void* d_out, int out_size, void* d_ws, size_t ws_size,
                              hipStream_t stream) {
  const float* x     = (const float*)d_in[0];
  const float* pos   = (const float*)d_in[1];
  const int*   eidx  = (const int*)d_in[2];
  const float* W_in  = (const float*)d_in[3];
  const float* b_in  = (const float*)d_in[4];
  const float* ln_g  = (const float*)d_in[5];
  const float* ln_b  = (const float*)d_in[6];
  const float* W_lin = (const float*)d_in[7];
  const float* W_src = (const float*)d_in[8];
  const float* W_dst = (const float*)d_in[9];
  const float* pn_W1 = (const float*)d_in[10];
  const float* pn_b1 = (const float*)d_in[11];
  const float* pn_W2 = (const float*)d_in[12];
  const float* pn_b2 = (const float*)d_in[13];
  const float* an_W1 = (const float*)d_in[14];
  const float* an_b1 = (const float*)d_in[15];
  const float* an_W2 = (const float*)d_in[16];
  const float* an_b2 = (const float*)d_in[17];
  const float* W_out = (const float*)d_in[18];
  const float* b_out = (const float*)d_in[19];
  float* out = (float*)d_out;

  int N = in_sizes[0] / 64;
  int E = in_sizes[2] / 2;
  const int* src = eidx;
  const int* dst = eidx + E;

  char* w = (char*)d_ws;
  auto alloc = [&](size_t bytes) -> void* {
    void* p = (void*)w;
    w += (bytes + 255) & ~(size_t)255;
    return p;
  };
  unsigned short* qg = (unsigned short*)alloc((size_t)N * 64 * 2);
  unsigned short* kg = (unsigned short*)alloc((size_t)N * 64 * 2);
  unsigned short* vg = (unsigned short*)alloc((size_t)N * 64 * 2);
  float* sg   = (float*)alloc((size_t)N * 64 * 4);
  float* accg = (float*)alloc((size_t)N * 64 * 4);   // contiguous after sg
  int2* spair = (int2*)alloc((size_t)E * 8);
  unsigned short* wt = (unsigned short*)alloc(8 * 4608 * 2);
  int* ccnt  = (int*)alloc(1024 * 4);
  int* cbase = (int*)alloc(1024 * 4);
  int2* pcoarse = (int2*)sg;   // CB*SRT_CAP*8B (~16MB) aliases sg (+accg);
                               // dead after k_s2, then memset zeroes sg/accg

  int CB = (N + 127) >> SRT_SH;                 // coarse buckets (<=1024)
  int s1Blocks = (E + SRT_EPB - 1) / SRT_EPB;
  int nodeBlocks = (N + 63) / 64;
  int numTiles = (E + 63) / 64;
  int edgeGrid = numTiles < 1024 ? numTiles : 1024;  // 4 blocks/CU x 256 CU

  hipMemsetAsync(ccnt, 0, 1024 * 4, stream);
  k_prep<<<8, 256, 0, stream>>>(
      W_in, W_dst, W_src, W_lin, pn_W2, an_W1, an_W2, W_out, wt);
  k_s1<<<s1Blocks, 256, 0, stream>>>(src, dst, E, CB, ccnt, pcoarse);
  k_s1scan<<<1, 256, 0, stream>>>(ccnt, cbase, CB);
  k_s2<<<CB, 256, 0, stream>>>(pcoarse, ccnt, cbase, spair);
  // pcoarse dead; zero sg+accg (contiguous) before k_edge accumulates
  hipMemsetAsync(sg, 0, (size_t)N * 64 * 4 * 2, stream);
  k_node<<<nodeBlocks, 256, 0, stream>>>(
      x, wt, b_in, ln_g, ln_b, qg, kg, vg, N);
  k_edge<<<edgeGrid, 256, 0, stream>>>(spair, pos, qg, kg, vg, wt,
                                       pn_W1, pn_b1, pn_b2, an_b1, an_b2,
                                       sg, accg, E, numTiles);
  k_out<<<nodeBlocks, 256, 0, stream>>>(accg, sg, wt, b_out, out, N);
}

// Round 14
// 371.296 us; speedup vs baseline: 1.4015x; 1.0420x over previous
//
#include <hip/hip_runtime.h>

// ---------------------------------------------------------------------------
// PointTransformerBlock, MI355X.  R26 = R25 + sort-window fusion; k_edge
// body UNTOUCHED:
//  R25 ledger: total 387 = k_edge 172 + tail 215 (model said ~90; close the
//  gap with structural overlap + fewer dispatches):
//  - k_s1 uses only 98 blocks -> 60% of CUs IDLE during it (block-level
//    underfill, unlike R23's stalled-wave-resident hist).  k_node is
//    independent of the sort -> FUSED as sibling blocks (s1 first 98,
//    node after) with an LDS overlay union (node 46.8KB / s1 12KB).
//  - pcoarse moved to its OWN workspace slice (no sg alias) -> sg/accg
//    zero-fill FUSED into k_s2's dispatch as sibling blocks (R22-proven
//    pattern); the 51.2MB memset dispatch is deleted.
//  - ccnt zeroing folded into k_prep (block 8).  9 dispatches+memsets -> 6.
//  - R25 sort logic verbatim (passed); R21/R24 k_edge verbatim.
//  MFMA layouts (HW-verified, guide §3): A[m=lane&15][k=q*8+j],
//  B[k=q*8+j][n=lane&15], C/D col=lane&15 row=q*4+r.
// ---------------------------------------------------------------------------

typedef __bf16 bf16x8 __attribute__((ext_vector_type(8)));
typedef float f32x4 __attribute__((ext_vector_type(4)));

#define SRT_SH   7          // coarse bucket = 128 dst values
#define SRT_CAP  2560       // padded coarse bucket capacity (mean 2048)
#define SRT_EPB  16384      // edges per k_s1 block

__device__ inline unsigned short f2bf(float f) {
  return __builtin_bit_cast(unsigned short, (__bf16)f);   // v_cvt (RNE)
}
__device__ inline float bf2f(unsigned short s) {
  return __uint_as_float(((unsigned int)s) << 16);
}
__device__ inline bf16x8 ld_bf8(const unsigned short* p) {
  union { uint4 i; bf16x8 v; } u;
  u.i = *(const uint4*)p;
  return u.v;
}
// packed f32->2xbf16 (gfx950; no builtin -- guide T12/m240). dst.lo=cvt(lo).
__device__ inline unsigned int cvt_pk_bf16(float lo, float hi) {
  unsigned int r;
  asm("v_cvt_pk_bf16_f32 %0, %1, %2" : "=v"(r) : "v"(lo), "v"(hi));
  return r;
}

// ------------- prep kernel (weights, 8 blocks; block 8 zeroes ccnt) --------

__global__ __launch_bounds__(256) void k_prep(
    const float* __restrict__ W_in, const float* __restrict__ W_dst,
    const float* __restrict__ W_src, const float* __restrict__ W_lin,
    const float* __restrict__ pn_W2, const float* __restrict__ an_W1,
    const float* __restrict__ an_W2, const float* __restrict__ W_out,
    unsigned short* __restrict__ wt, int* __restrict__ ccnt) {
  int t = threadIdx.x;
  if (blockIdx.x == 8) {
    if (t < 256) { ccnt[t] = 0; ccnt[256 + t] = 0; ccnt[512 + t] = 0;
                   ccnt[768 + t] = 0; }
    return;
  }
  const float* Ws[8] = {W_in, W_dst, W_src, W_lin, pn_W2, an_W1, an_W2, W_out};
  const float* W = Ws[blockIdx.x];
  unsigned short* o = wt + (size_t)blockIdx.x * 4608;
#pragma unroll
  for (int i = 0; i < 16; ++i) {
    int e = i * 256 + t;           // e = k*64 + n  (coalesced read)
    int k = e >> 6, n = e & 63;
    o[n * 72 + k] = f2bf(W[e]);    // wt[n][k] = W^T[n][k]
  }
}

// ------ fused: radix-sort coarse classify (98 blk) + node MFMA (rest) ------

__global__ __launch_bounds__(256) void k_s1_node(
    const int* __restrict__ src, const int* __restrict__ dst, int E, int CB,
    int* __restrict__ ccnt, int2* __restrict__ pcoarse, int s1Blocks,
    const float* __restrict__ x, const unsigned short* __restrict__ wt,
    const float* __restrict__ b_in, const float* __restrict__ ln_g,
    const float* __restrict__ ln_b,
    unsigned short* __restrict__ qg, unsigned short* __restrict__ kg,
    unsigned short* __restrict__ vg, int N) {
  // LDS overlay: node uses 46848B (WALL|HT|LNG|LNB|BIN); s1 uses 12288B.
  __shared__ __align__(16) unsigned char SH[46848];
  int t = threadIdx.x;

  if ((int)blockIdx.x < s1Blocks) {
    // ---------------- s1: coarse classify (R25 verbatim) ----------------
    int* hist = (int*)SH;
    int* offs = hist + 1024;
    int* cur  = offs + 1024;
    for (int i = t; i < 1024; i += 256) { hist[i] = 0; cur[i] = 0; }
    __syncthreads();
    long e0 = (long)blockIdx.x * SRT_EPB;
    int nE = (int)(((long)E - e0) < SRT_EPB ? ((long)E - e0) : SRT_EPB);
    for (int i = t; i < nE; i += 256)
      atomicAdd(&hist[dst[e0 + i] >> SRT_SH], 1);
    __syncthreads();
    for (int k = t; k < CB; k += 256) {
      int h = hist[k];
      offs[k] = (h > 0) ? atomicAdd(&ccnt[k], h) : 0;
    }
    __syncthreads();
    for (int i = t; i < nE; i += 256) {
      int s = src[e0 + i], d = dst[e0 + i];
      int k = d >> SRT_SH;
      int p = offs[k] + atomicAdd(&cur[k], 1);
      if (p < SRT_CAP) pcoarse[(size_t)k * SRT_CAP + p] = make_int2(s, d);
    }
    return;
  }

  // ---------------- node: transposed MFMA (R25 verbatim) ----------------
  unsigned short* WALL = (unsigned short*)SH;                // 4*64*72
  unsigned short* HT   = (unsigned short*)(SH + 36864);      // 64*72
  float* LNG = (float*)(SH + 46080);
  float* LNB = (float*)(SH + 46336);
  float* BIN = (float*)(SH + 46592);

  int lane = t & 63, wv = t >> 6;
  int nl = lane & 15, q = lane >> 4;
  int w16 = wv * 16;
  int n0g = ((int)blockIdx.x - s1Blocks) * 64;

  {
    const uint4* s4 = (const uint4*)wt;
    uint4* d4 = (uint4*)WALL;
#pragma unroll
    for (int i = 0; i < 9; ++i) d4[i * 256 + t] = s4[i * 256 + t];
  }
  if (t < 64) { LNG[t] = ln_g[t]; LNB[t] = ln_b[t]; BIN[t] = b_in[t]; }

  int row = n0g + w16 + nl;        // my node
  bf16x8 b[2];                     // B-frag: x[node=nl][k]
#pragma unroll
  for (int s = 0; s < 2; ++s) {
    union { unsigned int u[4]; bf16x8 v; } fb;
    if (row < N) {
      int kb = s * 32 + q * 8;
      float4 xa = *(const float4*)(x + (size_t)row * 64 + kb);
      float4 xb = *(const float4*)(x + (size_t)row * 64 + kb + 4);
      fb.u[0] = cvt_pk_bf16(xa.x, xa.y);
      fb.u[1] = cvt_pk_bf16(xa.z, xa.w);
      fb.u[2] = cvt_pk_bf16(xb.x, xb.y);
      fb.u[3] = cvt_pk_bf16(xb.z, xb.w);
    } else {
#pragma unroll
      for (int j = 0; j < 4; ++j) fb.u[j] = 0;
    }
    b[s] = fb.v;
  }
  __syncthreads();

  // GEMM1: h = relu(x @ W_in + b_in); lane holds ch m0*16+q*4+r of node nl
  f32x4 h[4];
#pragma unroll
  for (int m0 = 0; m0 < 4; ++m0) {
    f32x4 acc = *(const f32x4*)&BIN[m0 * 16 + q * 4];
    acc = __builtin_amdgcn_mfma_f32_16x16x32_bf16(
        ld_bf8(&WALL[(m0 * 16 + nl) * 72 + q * 8]), b[0], acc, 0, 0, 0);
    acc = __builtin_amdgcn_mfma_f32_16x16x32_bf16(
        ld_bf8(&WALL[(m0 * 16 + nl) * 72 + 32 + q * 8]), b[1], acc, 0, 0, 0);
#pragma unroll
    for (int r = 0; r < 4; ++r) acc[r] = fmaxf(acc[r], 0.f);
    h[m0] = acc;
  }

  // LayerNorm over channels of node nl: local 16 + reduce across q-lanes
  float sv = 0.f, sq = 0.f;
#pragma unroll
  for (int m0 = 0; m0 < 4; ++m0)
#pragma unroll
    for (int r = 0; r < 4; ++r) {
      float v = h[m0][r];
      sv += v; sq += v * v;
    }
  sv += __shfl_xor(sv, 16); sq += __shfl_xor(sq, 16);
  sv += __shfl_xor(sv, 32); sq += __shfl_xor(sq, 32);
  float mu = sv * (1.f / 64.f);
  float var = sq * (1.f / 64.f) - mu * mu;
  float rs = rsqrtf(var + 1e-5f);
#pragma unroll
  for (int m0 = 0; m0 < 4; ++m0) {
    f32x4 g4 = *(const f32x4*)&LNG[m0 * 16 + q * 4];
    f32x4 o4 = *(const f32x4*)&LNB[m0 * 16 + q * 4];
    float v0 = (h[m0][0] - mu) * rs * g4[0] + o4[0];
    float v1 = (h[m0][1] - mu) * rs * g4[1] + o4[1];
    float v2 = (h[m0][2] - mu) * rs * g4[2] + o4[2];
    float v3 = (h[m0][3] - mu) * rs * g4[3] + o4[3];
    uint2 pk;
    pk.x = cvt_pk_bf16(v0, v1);
    pk.y = cvt_pk_bf16(v2, v3);
    *(uint2*)&HT[(w16 + nl) * 72 + m0 * 16 + q * 4] = pk;
  }

  b[0] = ld_bf8(&HT[(w16 + nl) * 72 + q * 8]);
  b[1] = ld_bf8(&HT[(w16 + nl) * 72 + 32 + q * 8]);

  unsigned short* Og[3] = {qg, kg, vg};
  bool g = row < N;
#pragma unroll
  for (int m = 0; m < 3; ++m) {
    const unsigned short* Wm = WALL + (m + 1) * 4608;
#pragma unroll
    for (int m0 = 0; m0 < 4; ++m0) {
      f32x4 acc = {0.f, 0.f, 0.f, 0.f};
      acc = __builtin_amdgcn_mfma_f32_16x16x32_bf16(
          ld_bf8(&Wm[(m0 * 16 + nl) * 72 + q * 8]), b[0], acc, 0, 0, 0);
      acc = __builtin_amdgcn_mfma_f32_16x16x32_bf16(
          ld_bf8(&Wm[(m0 * 16 + nl) * 72 + 32 + q * 8]), b[1], acc, 0, 0, 0);
      if (g) {
        uint2 pk;
        pk.x = cvt_pk_bf16(acc[0], acc[1]);
        pk.y = cvt_pk_bf16(acc[2], acc[3]);
        // v (m==2) stored PERMUTED: pos(c)=q*16+m0*4+r so a k_edge lane
        // reads its 16 v-elems as one contiguous 32B block.  q/k unchanged.
        int off = (m == 2) ? (q * 16 + m0 * 4) : (m0 * 16 + q * 4);
        *(uint2*)(Og[m] + (size_t)row * 64 + off) = pk;
      }
    }
  }
}

// one-block exclusive scan of coarse counts (CB <= 1024)
__global__ __launch_bounds__(256) void k_s1scan(
    const int* __restrict__ ccnt, int* __restrict__ cbase, int CB) {
  __shared__ int sd[256];
  int t = threadIdx.x;
  int v[4]; int ts = 0;
#pragma unroll
  for (int i = 0; i < 4; ++i) {
    int idx = t * 4 + i;
    int c = (idx < CB) ? min(ccnt[idx], SRT_CAP) : 0;
    v[i] = c; ts += c;
  }
  sd[t] = ts;
  __syncthreads();
  for (int off = 1; off < 256; off <<= 1) {
    int xv = (t >= off) ? sd[t - off] : 0;
    __syncthreads();
    sd[t] += xv;
    __syncthreads();
  }
  int run = sd[t] - ts;
#pragma unroll
  for (int i = 0; i < 4; ++i) {
    int idx = t * 4 + i;
    if (idx < CB) cbase[idx] = run;
    run += v[i];
  }
}

// ------ fused: per-bucket refine (CB blocks) + sg/accg zero (rest) ---------

__global__ __launch_bounds__(256) void k_s2_zero(
    const int2* __restrict__ pcoarse, const int* __restrict__ ccnt,
    const int* __restrict__ cbase, int2* __restrict__ spair, int CB,
    float4* __restrict__ zbase, int zcount) {
  int t = threadIdx.x;
  if ((int)blockIdx.x >= CB) {
    int i = ((int)blockIdx.x - CB) * 256 + t;
    if (i < zcount) zbase[i] = make_float4(0.f, 0.f, 0.f, 0.f);
    return;
  }
  __shared__ int dh[128], dcur[128], dbase[128], sd[128];
  int k = blockIdx.x;
  if (t < 128) { dh[t] = 0; dcur[t] = 0; }
  __syncthreads();
  int cnt = min(ccnt[k], SRT_CAP);
  const int2* bb = pcoarse + (size_t)k * SRT_CAP;
  int dlo = k << SRT_SH;
  for (int i = t; i < cnt; i += 256)
    atomicAdd(&dh[bb[i].y - dlo], 1);
  __syncthreads();
  if (t < 128) sd[t] = dh[t];
  __syncthreads();
  for (int off = 1; off < 128; off <<= 1) {
    int xv = 0;
    if (t < 128 && t >= off) xv = sd[t - off];
    __syncthreads();
    if (t < 128) sd[t] += xv;
    __syncthreads();
  }
  if (t < 128) dbase[t] = cbase[k] + sd[t] - dh[t];
  __syncthreads();
  for (int i = t; i < cnt; i += 256) {
    int2 e = bb[i];
    int j = e.y - dlo;
    int p = dbase[j] + atomicAdd(&dcur[j], 1);
    spair[p] = e;
  }
}

// ---- edge kernel (persistent, 4 blocks/CU, R21/R24 body verbatim) ---------

__global__ __launch_bounds__(256, 4) void k_edge(
    const int2* __restrict__ spair, const float* __restrict__ pos,
    const unsigned short* __restrict__ qg, const unsigned short* __restrict__ kg,
    const unsigned short* __restrict__ vg,
    const unsigned short* __restrict__ wt,
    const float* __restrict__ pn_W1, const float* __restrict__ pn_b1,
    const float* __restrict__ pn_b2,
    const float* __restrict__ an_b1, const float* __restrict__ an_b2,
    float* __restrict__ sg, float* __restrict__ accg, int E, int numTiles) {
  __shared__ __align__(16) unsigned short WAB[2 * 64 * 72];  // pn_W2 | an_W1
  __shared__ __align__(16) unsigned short SD[64 * 72];   // delta, then pay
  __shared__ __align__(16) unsigned short SB[64 * 72];   // a1, then ex
  __shared__ float W1[3 * 64];
  __shared__ float B1[64];
  __shared__ __align__(16) float B2[64], AB1[64], AB2[64];

  int t = threadIdx.x;
  int lane = t & 63, wv = t >> 6;
  int nl = lane & 15, q = lane >> 4;
  int w16 = wv * 16;

  // ---- one-time staging: pn_W2 + an_W1 to LDS (uint4 memcpy) ----
  {
    const uint4* s4 = (const uint4*)(wt + 4 * 4608);  // matrices 4,5
    uint4* d4 = (uint4*)WAB;
#pragma unroll
    for (int i = 0; i < 5; ++i) {
      int idx = i * 256 + t;
      if (idx < 1152) d4[idx] = s4[idx];
    }
  }
  if (t < 192) W1[t] = pn_W1[t];
  if (t < 64) {
    B1[t] = pn_b1[t];  B2[t] = pn_b2[t];
    AB1[t] = an_b1[t]; AB2[t] = an_b2[t];
  }
  // ---- an_W2 A-frags -> registers (32 VGPR), straight from wt ----
  bf16x8 wan2r[8];
#pragma unroll
  for (int m0 = 0; m0 < 4; ++m0)
#pragma unroll
    for (int s = 0; s < 2; ++s)
      wan2r[m0 * 2 + s] =
          ld_bf8(wt + 6 * 4608 + (m0 * 16 + nl) * 72 + s * 32 + q * 8);
  const unsigned short* WPN2 = WAB;
  const unsigned short* WAN1 = WAB + 4608;
  __syncthreads();   // the ONLY barrier: weights/biases visible to all waves

  // Lane L of wave wv owns edge e0 + w16 + (L&15): its (src,dst) pair "my"
  // IS the tile's cross-lane state (distributed via __shfl, no LDS, no
  // barriers; SD/SB strips rows w16..w16+15 stay wave-private).
  long er_off = w16 + nl;
  int2 my;
  {
    long er = (long)blockIdx.x * 64 + er_off;
    my = (er < E) ? spair[er] : make_int2(0, 0);
  }

  for (int tile = blockIdx.x; tile < numTiles; tile += gridDim.x) {
    long e0 = (long)tile * 64;

    // ---- tile-top fan-out: all gathers issue off prefetched "my" ----
    const unsigned short* qr = qg + (size_t)my.y * 64;
    const unsigned short* kr = kg + (size_t)my.x * 64;
    bf16x8 qf[2], kf[2];
#pragma unroll
    for (int s = 0; s < 2; ++s) {
      int kb = s * 32 + q * 8;
      qf[s] = ld_bf8(qr + kb);
      kf[s] = ld_bf8(kr + kb);
    }
    // v for my OWN edge's src: PERMUTED layout -> one contiguous 32B
    const unsigned short* vr = vg + (size_t)my.x * 64;
    bf16x8 vlo = ld_bf8(vr + q * 16);
    bf16x8 vhi = ld_bf8(vr + q * 16 + 8);
    // pos diffs for my own edge (strip row w16+nl == my edge)
    float p0 = pos[my.y * 3 + 0] - pos[my.x * 3 + 0];
    float p1 = pos[my.y * 3 + 1] - pos[my.x * 3 + 1];
    float p2 = pos[my.y * 3 + 2] - pos[my.x * 3 + 2];

    // ---- prefetch next tile's spair into regs (hide under compute) ----
    int2 nxt = make_int2(0, 0);
    {
      long ntile = (long)tile + gridDim.x;
      if (ntile < numTiles) {
        long ner = ntile * 64 + er_off;
        nxt = (ner < E) ? spair[ner] : make_int2(0, 0);
      }
    }

    bool elive = (e0 + er_off) < E;   // my edge's liveness (col = nl)

    bf16x8 b[2];

    // ---- pos-MLP layer1 (K=3) straight into B-frag registers ----
#pragma unroll
    for (int s = 0; s < 2; ++s) {
      union { unsigned int u[4]; bf16x8 v; } fb;
      int kb = s * 32 + q * 8;
#pragma unroll
      for (int jj = 0; jj < 4; ++jj) {
        int c0 = kb + 2 * jj, c1 = c0 + 1;
        float v0 = fmaf(p0, W1[c0],
                   fmaf(p1, W1[64 + c0],
                   fmaf(p2, W1[128 + c0], B1[c0])));
        float v1 = fmaf(p0, W1[c1],
                   fmaf(p1, W1[64 + c1],
                   fmaf(p2, W1[128 + c1], B1[c1])));
        fb.u[jj] = cvt_pk_bf16(fmaxf(v0, 0.f), fmaxf(v1, 0.f));
      }
      b[s] = fb.v;
    }

    // ---- GEMM1: delta^T = pn_W2^T @ A1^T, bias-in-acc, relu -> SD ----
    f32x4 dlt[4];
#pragma unroll
    for (int m0 = 0; m0 < 4; ++m0) {
      f32x4 acc = *(const f32x4*)&B2[m0 * 16 + q * 4];
      acc = __builtin_amdgcn_mfma_f32_16x16x32_bf16(
          ld_bf8(&WPN2[(m0 * 16 + nl) * 72 + q * 8]), b[0], acc, 0, 0, 0);
      acc = __builtin_amdgcn_mfma_f32_16x16x32_bf16(
          ld_bf8(&WPN2[(m0 * 16 + nl) * 72 + 32 + q * 8]), b[1], acc, 0, 0, 0);
#pragma unroll
      for (int r = 0; r < 4; ++r) acc[r] = fmaxf(acc[r], 0.f);
      dlt[m0] = acc;
      uint2 pk;
      pk.x = cvt_pk_bf16(acc[0], acc[1]);
      pk.y = cvt_pk_bf16(acc[2], acc[3]);
      *(uint2*)&SD[(w16 + nl) * 72 + m0 * 16 + q * 4] = pk;
    }

    // ---- build ai = q[dst]-k[src]+delta in B-frag layout (reads SD) ----
#pragma unroll
    for (int s = 0; s < 2; ++s) {
      int kb = s * 32 + q * 8;
      bf16x8 d8 = ld_bf8(&SD[(w16 + nl) * 72 + kb]);
      union { unsigned int u[4]; bf16x8 v; } fb;
#pragma unroll
      for (int jj = 0; jj < 4; ++jj) {
        float v0 = (float)qf[s][2 * jj]     - (float)kf[s][2 * jj]     + (float)d8[2 * jj];
        float v1 = (float)qf[s][2 * jj + 1] - (float)kf[s][2 * jj + 1] + (float)d8[2 * jj + 1];
        fb.u[jj] = cvt_pk_bf16(v0, v1);
      }
      b[s] = fb.v;
    }

    // ---- overwrite SD with pay = delta + v[src]  (same-wave DS order) ----
#pragma unroll
    for (int m0 = 0; m0 < 4; ++m0) {
      float va0, va1, va2, va3;
      if (m0 == 0)      { va0 = (float)vlo[0]; va1 = (float)vlo[1];
                          va2 = (float)vlo[2]; va3 = (float)vlo[3]; }
      else if (m0 == 1) { va0 = (float)vlo[4]; va1 = (float)vlo[5];
                          va2 = (float)vlo[6]; va3 = (float)vlo[7]; }
      else if (m0 == 2) { va0 = (float)vhi[0]; va1 = (float)vhi[1];
                          va2 = (float)vhi[2]; va3 = (float)vhi[3]; }
      else              { va0 = (float)vhi[4]; va1 = (float)vhi[5];
                          va2 = (float)vhi[6]; va3 = (float)vhi[7]; }
      uint2 pk;
      pk.x = cvt_pk_bf16(dlt[m0][0] + va0, dlt[m0][1] + va1);
      pk.y = cvt_pk_bf16(dlt[m0][2] + va2, dlt[m0][3] + va3);
      *(uint2*)&SD[(w16 + nl) * 72 + m0 * 16 + q * 4] = pk;
    }

    // ---- GEMM2: a1^T = an_W1^T @ ai^T, bias-in-acc, relu -> SB ----
#pragma unroll
    for (int m0 = 0; m0 < 4; ++m0) {
      f32x4 acc = *(const f32x4*)&AB1[m0 * 16 + q * 4];
      acc = __builtin_amdgcn_mfma_f32_16x16x32_bf16(
          ld_bf8(&WAN1[(m0 * 16 + nl) * 72 + q * 8]), b[0], acc, 0, 0, 0);
      acc = __builtin_amdgcn_mfma_f32_16x16x32_bf16(
          ld_bf8(&WAN1[(m0 * 16 + nl) * 72 + 32 + q * 8]), b[1], acc, 0, 0, 0);
      uint2 pk;
      pk.x = cvt_pk_bf16(fmaxf(acc[0], 0.f), fmaxf(acc[1], 0.f));
      pk.y = cvt_pk_bf16(fmaxf(acc[2], 0.f), fmaxf(acc[3], 0.f));
      *(uint2*)&SB[(w16 + nl) * 72 + m0 * 16 + q * 4] = pk;
    }

    // ---- GEMM3: alpha^T = an_W2^T(regs) @ a1^T; ex = exp(relu) -> SB ----
    b[0] = ld_bf8(&SB[(w16 + nl) * 72 + q * 8]);
    b[1] = ld_bf8(&SB[(w16 + nl) * 72 + 32 + q * 8]);
#pragma unroll
    for (int m0 = 0; m0 < 4; ++m0) {
      f32x4 acc = *(const f32x4*)&AB2[m0 * 16 + q * 4];
      acc = __builtin_amdgcn_mfma_f32_16x16x32_bf16(
          wan2r[m0 * 2 + 0], b[0], acc, 0, 0, 0);
      acc = __builtin_amdgcn_mfma_f32_16x16x32_bf16(
          wan2r[m0 * 2 + 1], b[1], acc, 0, 0, 0);
      float e0v = elive ? __expf(fmaxf(acc[0], 0.f)) : 0.f;
      float e1v = elive ? __expf(fmaxf(acc[1], 0.f)) : 0.f;
      float e2v = elive ? __expf(fmaxf(acc[2], 0.f)) : 0.f;
      float e3v = elive ? __expf(fmaxf(acc[3], 0.f)) : 0.f;
      uint2 pk;
      pk.x = cvt_pk_bf16(e0v, e1v);
      pk.y = cvt_pk_bf16(e2v, e3v);
      *(uint2*)&SB[(w16 + nl) * 72 + m0 * 16 + q * 4] = pk;
    }

    // ---- segmented per-dst-run reduction (dst runs via shuffle) ----
    {
      int c = lane;
      int cur = __shfl(my.y, 0);
      float ssum = 0.f, asum = 0.f;
#pragma unroll
      for (int i = 0; i < 16; ++i) {
        int d = __shfl(my.y, i);
        if (d != cur) {
          if (ssum != 0.f) {
            atomicAdd(&sg[(size_t)cur * 64 + c], ssum);
            atomicAdd(&accg[(size_t)cur * 64 + c], asum);
          }
          cur = d; ssum = 0.f; asum = 0.f;
        }
        float ex = bf2f(SB[(w16 + i) * 72 + c]);
        float pay = bf2f(SD[(w16 + i) * 72 + c]);   // pay = delta + v
        ssum += ex;
        asum = fmaf(ex, pay, asum);
      }
      if (ssum != 0.f) {
        atomicAdd(&sg[(size_t)cur * 64 + c], ssum);
        atomicAdd(&accg[(size_t)cur * 64 + c], asum);
      }
    }

    my = nxt;   // rotate prefetched pair
  }
}

// ------------------------- out kernel (transposed MFMA) --------------------

__global__ __launch_bounds__(256) void k_out(const float* __restrict__ accg,
                                             const float* __restrict__ sg,
                                             const unsigned short* __restrict__ wt,
                                             const float* __restrict__ b,
                                             float* __restrict__ out, int N) {
  __shared__ __align__(16) unsigned short WO[64 * 72];
  __shared__ __align__(16) float BO[64];
  int t = threadIdx.x;
  int lane = t & 63, wv = t >> 6;
  int nl = lane & 15, q = lane >> 4;
  int w16 = wv * 16;
  int n0g = blockIdx.x * 64;

  {
    const uint4* s4 = (const uint4*)(wt + 7 * 4608);  // matrix 7 = W_out
    uint4* d4 = (uint4*)WO;
#pragma unroll
    for (int i = 0; i < 3; ++i) {
      int idx = i * 256 + t;
      if (idx < 576) d4[idx] = s4[idx];
    }
  }
  if (t < 64) BO[t] = b[t];

  int row = n0g + w16 + nl;        // my node
  bf16x8 bb[2];
#pragma unroll
  for (int s = 0; s < 2; ++s) {
    union { unsigned int u[4]; bf16x8 v; } fb;
    if (row < N) {
      int kb = s * 32 + q * 8;
      float4 na = *(const float4*)(accg + (size_t)row * 64 + kb);
      float4 nb = *(const float4*)(accg + (size_t)row * 64 + kb + 4);
      float4 da = *(const float4*)(sg + (size_t)row * 64 + kb);
      float4 db = *(const float4*)(sg + (size_t)row * 64 + kb + 4);
      fb.u[0] = cvt_pk_bf16(na.x / (da.x + 1e-16f), na.y / (da.y + 1e-16f));
      fb.u[1] = cvt_pk_bf16(na.z / (da.z + 1e-16f), na.w / (da.w + 1e-16f));
      fb.u[2] = cvt_pk_bf16(nb.x / (db.x + 1e-16f), nb.y / (db.y + 1e-16f));
      fb.u[3] = cvt_pk_bf16(nb.z / (db.z + 1e-16f), nb.w / (db.w + 1e-16f));
    } else {
#pragma unroll
      for (int j = 0; j < 4; ++j) fb.u[j] = 0;
    }
    bb[s] = fb.v;
  }
  __syncthreads();

  bool g = row < N;
#pragma unroll
  for (int m0 = 0; m0 < 4; ++m0) {
    f32x4 acc = *(const f32x4*)&BO[m0 * 16 + q * 4];
    acc = __builtin_amdgcn_mfma_f32_16x16x32_bf16(
        ld_bf8(&WO[(m0 * 16 + nl) * 72 + q * 8]), bb[0], acc, 0, 0, 0);
    acc = __builtin_amdgcn_mfma_f32_16x16x32_bf16(
        ld_bf8(&WO[(m0 * 16 + nl) * 72 + 32 + q * 8]), bb[1], acc, 0, 0, 0);
    if (g) {
      float4 o;
      o.x = fmaxf(acc[0], 0.f);
      o.y = fmaxf(acc[1], 0.f);
      o.z = fmaxf(acc[2], 0.f);
      o.w = fmaxf(acc[3], 0.f);
      *(float4*)(out + (size_t)row * 64 + m0 * 16 + q * 4) = o;
    }
  }
}

// ------------------------------- launcher ----------------------------------

extern "C" void kernel_launch(void* const* d_in, const int* in_sizes, int n_in,
                              void* d_out, int out_size, void* d_ws, size_t ws_size,
                              hipStream_t stream) {
  const float* x     = (const float*)d_in[0];
  const float* pos   = (const float*)d_in[1];
  const int*   eidx  = (const int*)d_in[2];
  const float* W_in  = (const float*)d_in[3];
  const float* b_in  = (const float*)d_in[4];
  const float* ln_g  = (const float*)d_in[5];
  const float* ln_b  = (const float*)d_in[6];
  const float* W_lin = (const float*)d_in[7];
  const float* W_src = (const float*)d_in[8];
  const float* W_dst = (const float*)d_in[9];
  const float* pn_W1 = (const float*)d_in[10];
  const float* pn_b1 = (const float*)d_in[11];
  const float* pn_W2 = (const float*)d_in[12];
  const float* pn_b2 = (const float*)d_in[13];
  const float* an_W1 = (const float*)d_in[14];
  const float* an_b1 = (const float*)d_in[15];
  const float* an_W2 = (const float*)d_in[16];
  const float* an_b2 = (const float*)d_in[17];
  const float* W_out = (const float*)d_in[18];
  const float* b_out = (const float*)d_in[19];
  float* out = (float*)d_out;

  int N = in_sizes[0] / 64;
  int E = in_sizes[2] / 2;
  const int* src = eidx;
  const int* dst = eidx + E;

  char* w = (char*)d_ws;
  auto alloc = [&](size_t bytes) -> void* {
    void* p = (void*)w;
    w += (bytes + 255) & ~(size_t)255;
    return p;
  };
  unsigned short* qg = (unsigned short*)alloc((size_t)N * 64 * 2);
  unsigned short* kg = (unsigned short*)alloc((size_t)N * 64 * 2);
  unsigned short* vg = (unsigned short*)alloc((size_t)N * 64 * 2);
  float* sg   = (float*)alloc((size_t)N * 64 * 4);
  float* accg = (float*)alloc((size_t)N * 64 * 4);   // contiguous after sg
  int2* spair = (int2*)alloc((size_t)E * 8);
  unsigned short* wt = (unsigned short*)alloc(8 * 4608 * 2);
  int* ccnt  = (int*)alloc(1024 * 4);
  int* cbase = (int*)alloc(1024 * 4);
  int2* pcoarse = (int2*)alloc((size_t)1024 * SRT_CAP * 8);  // own slice

  int CB = (N + 127) >> SRT_SH;                 // coarse buckets (<=1024)
  int s1Blocks = (E + SRT_EPB - 1) / SRT_EPB;
  int nodeBlocks = (N + 63) / 64;
  int zcount = N * 32;                          // sg+accg in float4s
  int zBlocks = (zcount + 255) / 256;
  int numTiles = (E + 63) / 64;
  int edgeGrid = numTiles < 1024 ? numTiles : 1024;  // 4 blocks/CU x 256 CU

  k_prep<<<9, 256, 0, stream>>>(
      W_in, W_dst, W_src, W_lin, pn_W2, an_W1, an_W2, W_out, wt, ccnt);
  k_s1_node<<<s1Blocks + nodeBlocks, 256, 0, stream>>>(
      src, dst, E, CB, ccnt, pcoarse, s1Blocks,
      x, wt, b_in, ln_g, ln_b, qg, kg, vg, N);
  k_s1scan<<<1, 256, 0, stream>>>(ccnt, cbase, CB);
  k_s2_zero<<<CB + zBlocks, 256, 0, stream>>>(
      pcoarse, ccnt, cbase, spair, CB, (float4*)sg, zcount);
  k_edge<<<edgeGrid, 256, 0, stream>>>(spair, pos, qg, kg, vg, wt,
                                       pn_W1, pn_b1, pn_b2, an_b1, an_b2,
                                       sg, accg, E, numTiles);
  k_out<<<nodeBlocks, 256, 0, stream>>>(accg, sg, wt, b_out, out, N);
}